// Round 4
// baseline (263.242 us; speedup 1.0000x reference)
//
#include <hip/hip_runtime.h>
#include <stdint.h>

typedef __attribute__((ext_vector_type(8))) short short8;       // 8 x bf16
typedef __attribute__((ext_vector_type(4))) float f32x4;
typedef __attribute__((ext_vector_type(4))) unsigned short ushort4_;
typedef __attribute__((ext_vector_type(4))) unsigned int uint4_;
typedef __attribute__((ext_vector_type(2))) unsigned int uint2_;

#define MFMA16(a, b, c) __builtin_amdgcn_mfma_f32_16x16x32_bf16((a), (b), (c), 0, 0, 0)

static __device__ __forceinline__ unsigned short f2bf(float f) {
    unsigned u = __float_as_uint(f);
    u += 0x7fffu + ((u >> 16) & 1u);   // RNE
    return (unsigned short)(u >> 16);
}

static __device__ __forceinline__ float bf2f(unsigned short u) {
    return __uint_as_float(((unsigned)u) << 16);
}

static __device__ __forceinline__ float exp2_fast(float x) {
#if __has_builtin(__builtin_amdgcn_exp2f)
    return __builtin_amdgcn_exp2f(x);
#else
    return exp2f(x);
#endif
}

static __device__ __forceinline__ unsigned cvt_pk(float lo, float hi) {
    unsigned r;
    asm("v_cvt_pk_bf16_f32 %0, %1, %2" : "=v"(r) : "v"(lo), "v"(hi));
    return r;
}

static __device__ __forceinline__ short8 pack8(float a0, float a1, float a2, float a3,
                                               float a4, float a5, float a6, float a7) {
    union { uint4_ u; short8 s; } c;
    c.u[0] = cvt_pk(a0, a1); c.u[1] = cvt_pk(a2, a3);
    c.u[2] = cvt_pk(a4, a5); c.u[3] = cvt_pk(a6, a7);
    return c.s;
}

static __device__ __forceinline__ ushort4_ pack4(float a0, float a1, float a2, float a3) {
    union { uint2_ u; ushort4_ s; } c;
    c.u[0] = cvt_pk(a0, a1); c.u[1] = cvt_pk(a2, a3);
    return c.s;
}

#define GLOAD16(SRC, DSTPTR) __builtin_amdgcn_global_load_lds(                       \
    (const __attribute__((address_space(1))) void*)(SRC),                            \
    (__attribute__((address_space(3))) void*)(DSTPTR), 16, 0, 0)

// ---------------------------------------------------------------------------
// Kernel 0: W (3 heads, f32) -> bf16, contiguous Wb[3][128][1024]
// ---------------------------------------------------------------------------
__global__ __launch_bounds__(256) void wcvt_kernel(
    const float* __restrict__ Wq, const float* __restrict__ Wk, const float* __restrict__ Wv,
    unsigned short* __restrict__ Wb)
{
    const int hd = blockIdx.y;
    const float* W = (hd == 0) ? Wq : ((hd == 1) ? Wk : Wv);
    const int idx = (blockIdx.x * 256 + threadIdx.x) * 4;
    f32x4 v = *(const f32x4*)(W + idx);
    ushort4_ o;
#pragma unroll
    for (int j = 0; j < 4; ++j) o[j] = f2bf(v[j]);
    *(ushort4_*)(Wb + (size_t)hd * 131072 + idx) = o;
}

// ---------------------------------------------------------------------------
// Kernel 1: fused QKV. M-tile 32, 512 threads (8 waves x 3 cfgs), grid 256.
// X read once (staged bf16 in LDS, reg-prefetch pipeline); W bf16 fragments
// direct from L2 with register double-buffer.
//   head0: Q * log2(e)/sqrt(128) -> Qs ; head1: K -> Kb ; head2: V -> Vt^T
// ---------------------------------------------------------------------------
__global__ __launch_bounds__(512, 2) void qkv_kernel(
    const float* __restrict__ X, const unsigned short* __restrict__ Wb,
    unsigned short* __restrict__ Qs, unsigned short* __restrict__ Kb, unsigned short* __restrict__ Vt)
{
    __shared__ __align__(16) char lds[4096];    // X slice: 32 rows x 64 bf16
    const int tid = threadIdx.x, lane = tid & 63, wid = tid >> 6;
    const int lrow = lane & 15, lgrp = lane >> 4;
    const int m0 = blockIdx.x * 32;

    const int xrow = tid >> 4, xseg = tid & 15;    // 32 rows x 16 segs x 4 f32
    const int xsw = (xrow & 7) << 4;
    const int xoff = xrow * 128 + (((xseg >> 1) * 16) ^ xsw) + (xseg & 1) * 8;
    const float* xbase = X + (size_t)(m0 + xrow) * 1024 + xseg * 4;

    const unsigned short* wp[3];
#pragma unroll
    for (int i = 0; i < 3; ++i) {
        const int cfg = wid * 3 + i;
        wp[i] = Wb + (size_t)(cfg >> 3) * 131072 + (size_t)((cfg & 7) * 16 + lrow) * 1024 + lgrp * 8;
    }

    f32x4 acc[2][3];
#pragma unroll
    for (int mi = 0; mi < 2; ++mi)
#pragma unroll
        for (int i = 0; i < 3; ++i) acc[mi][i] = (f32x4)0.0f;

    f32x4 xr;
    short8 wa[3][2], wb2[3][2];

    // prologue: X(0) -> LDS; W(0) -> wa; X(1) -> xr
    xr = *(const f32x4*)(xbase);
#pragma unroll
    for (int i = 0; i < 3; ++i) {
        wa[i][0] = *(const short8*)(wp[i]);
        wa[i][1] = *(const short8*)(wp[i] + 32);
    }
    *(ushort4_*)(lds + xoff) = pack4(xr[0], xr[1], xr[2], xr[3]);
    xr = *(const f32x4*)(xbase + 64);
    __syncthreads();

#define QKV_STEP(WC, WN, S)                                                          \
    do {                                                                             \
        if ((S) < 15) {                                                              \
            _Pragma("unroll")                                                        \
            for (int i = 0; i < 3; ++i) {                                            \
                WN[i][0] = *(const short8*)(wp[i] + ((S) + 1) * 64);                 \
                WN[i][1] = *(const short8*)(wp[i] + ((S) + 1) * 64 + 32);            \
            }                                                                        \
        }                                                                            \
        __builtin_amdgcn_s_setprio(1);                                               \
        _Pragma("unroll")                                                            \
        for (int kc = 0; kc < 2; ++kc) {                                             \
            short8 a[2];                                                             \
            _Pragma("unroll")                                                        \
            for (int mi = 0; mi < 2; ++mi)                                           \
                a[mi] = *(const short8*)(lds + (mi * 16 + lrow) * 128 +              \
                          ((kc * 64 + lgrp * 16) ^ ((lrow & 7) << 4)));              \
            _Pragma("unroll")                                                        \
            for (int i = 0; i < 3; ++i)                                              \
                _Pragma("unroll")                                                    \
                for (int mi = 0; mi < 2; ++mi)                                       \
                    acc[mi][i] = MFMA16(a[mi], WC[i][kc], acc[mi][i]);               \
        }                                                                            \
        __builtin_amdgcn_s_setprio(0);                                               \
        if ((S) < 15) {                                                              \
            __syncthreads();                                                         \
            *(ushort4_*)(lds + xoff) = pack4(xr[0], xr[1], xr[2], xr[3]);            \
            if ((S) < 14) xr = *(const f32x4*)(xbase + ((S) + 2) * 64);              \
            __syncthreads();                                                         \
        }                                                                            \
    } while (0)

#pragma unroll
    for (int ss = 0; ss < 8; ++ss) {
        QKV_STEP(wa, wb2, 2 * ss);
        QKV_STEP(wb2, wa, 2 * ss + 1);
    }
#undef QKV_STEP

    const float qscale = 0.12752039f;   // log2(e)/sqrt(128)
#pragma unroll
    for (int i = 0; i < 3; ++i) {
        const int cfg = wid * 3 + i;
        const int head = cfg >> 3, cf = cfg & 7;
        if (head < 2) {
            unsigned short* dst = (head == 0) ? Qs : Kb;
            const float sc = (head == 0) ? qscale : 1.0f;
#pragma unroll
            for (int mi = 0; mi < 2; ++mi)
#pragma unroll
                for (int r = 0; r < 4; ++r) {
                    const int row = m0 + mi * 16 + lgrp * 4 + r;
                    dst[(size_t)row * 128 + cf * 16 + lrow] = f2bf(acc[mi][i][r] * sc);
                }
        } else {
#pragma unroll
            for (int mi = 0; mi < 2; ++mi) {
                ushort4_ v;
#pragma unroll
                for (int r = 0; r < 4; ++r) v[r] = f2bf(acc[mi][i][r]);
                *(ushort4_*)(Vt + (size_t)(cf * 16 + lrow) * 8192 + m0 + mi * 16 + lgrp * 4) = v;
            }
        }
    }
}

// ---------------------------------------------------------------------------
// Kernel 2: flash-attention partial.
// grid 512 = 64 q-tiles(128 rows) x 8 kv-splits(1024). Block 256 = 4 waves,
// each wave 32 q-rows. One shared K tile (KVBLK=32) per block, dbuf LDS 16KB,
// staged via global_load_lds w16 (sigma-permuted + XOR-swizzled source).
// V direct global->reg. One barrier/iter. 2 blocks/CU -> 16 waves/CU.
// Writes bf16 unnormalized partial O + f32 (m,l) per row.
// ---------------------------------------------------------------------------
__global__ __launch_bounds__(256, 4) void attn_kernel(
    const unsigned short* __restrict__ Qs,
    const unsigned short* __restrict__ Kb,
    const unsigned short* __restrict__ Vt,
    unsigned short* __restrict__ partO, float* __restrict__ partML)
{
    __shared__ __align__(16) char lds[16384];   // K dbuf 2 x 8KB
    const int tid = threadIdx.x, lane = tid & 63, wid = tid >> 6;
    const int lrow = lane & 15, lgrp = lane >> 4;
    const int qtile = blockIdx.x >> 3, sp = blockIdx.x & 7;
    const int qb = qtile * 128 + wid * 32;
    const int kvstart = sp * 1024;

    // --- K staging: 2 gloads/thread; LDS linear, source sigma+swizzle ---
    const char* ksrc[2];
    char* kdst[2];
#pragma unroll
    for (int g = 0; g < 2; ++g) {
        const int slot = g * 16 + wid * 4 + (lane >> 4);
        const int krow = ((slot >> 2) & 3) * 8 + ((slot >> 4) & 1) * 4 + (slot & 3);
        const int off = 16 * ((lane & 15) ^ (slot & 15));
        ksrc[g] = (const char*)Kb + (size_t)(kvstart + krow) * 256 + off;
        kdst[g] = lds + g * 4096 + wid * 1024;   // +buf*8192; lane*16 implicit
    }
    // --- V fragment base (direct global, L2-resident) ---
    const char* vbyte = (const char*)Vt + (size_t)lrow * 16384 + (size_t)kvstart * 2 + lgrp * 16;

    // Q fragments: lane holds Q[qb + j*16 + lrow][c*32 + lgrp*8 ..]
    short8 qf[2][4];
#pragma unroll
    for (int j = 0; j < 2; ++j)
#pragma unroll
        for (int c = 0; c < 4; ++c)
            qf[j][c] = *(const short8*)(Qs + (size_t)(qb + j * 16 + lrow) * 128 + c * 32 + lgrp * 8);

    f32x4 o[2][8];
#pragma unroll
    for (int j = 0; j < 2; ++j)
#pragma unroll
        for (int i = 0; i < 8; ++i) o[j][i] = (f32x4)0.0f;
    float m[2] = { -1e30f, -1e30f }, l[2] = { 0.0f, 0.0f };

    // prologue: K(0) -> buf 0
#pragma unroll
    for (int g = 0; g < 2; ++g) GLOAD16(ksrc[g], kdst[g]);
    asm volatile("s_waitcnt vmcnt(0)" ::: "memory");
    __syncthreads();

    for (int t = 0; t < 32; ++t) {
        const int buf = t & 1;
        if (t < 31) {   // K(t+1) -> other buffer; in flight across this iter
#pragma unroll
            for (int g = 0; g < 2; ++g)
                GLOAD16(ksrc[g] + (size_t)(t + 1) * 8192, kdst[g] + (buf ^ 1) * 8192);
        }
        short8 vr[8];   // V fragments for tile t
#pragma unroll
        for (int df = 0; df < 8; ++df)
            vr[df] = *(const short8*)(vbyte + (size_t)df * 262144 + t * 64);

        const char* kb = lds + buf * 8192;

        // ---- S^T = K Q (exp2 domain; scale folded into Q) ----
        f32x4 s[2][2];
        s[0][0] = s[0][1] = s[1][0] = s[1][1] = (f32x4)0.0f;
        __builtin_amdgcn_s_setprio(1);
#pragma unroll
        for (int f = 0; f < 2; ++f) {
            const int rbase = (f * 16 + lrow) * 256;
            const int swz = lrow << 4;
#pragma unroll
            for (int c = 0; c < 4; ++c) {
                short8 kf = *(const short8*)(kb + rbase + ((c * 64 + lgrp * 16) ^ swz));
                s[0][f] = MFMA16(kf, qf[0][c], s[0][f]);
                s[1][f] = MFMA16(kf, qf[1][c], s[1][f]);
            }
        }
        __builtin_amdgcn_s_setprio(0);

        // ---- online softmax: lane owns q=lane&15 (per j), kv = 8*lgrp+4f+r ----
        float tm[2];
#pragma unroll
        for (int j = 0; j < 2; ++j) {
            float t0 = fmaxf(fmaxf(s[j][0][0], s[j][0][1]), fmaxf(s[j][0][2], s[j][0][3]));
            float t1 = fmaxf(fmaxf(s[j][1][0], s[j][1][1]), fmaxf(s[j][1][2], s[j][1][3]));
            float t2 = fmaxf(t0, t1);
            t2 = fmaxf(t2, __shfl_xor(t2, 16));
            t2 = fmaxf(t2, __shfl_xor(t2, 32));
            tm[j] = t2;
        }
        const bool need = (tm[0] > m[0] + 8.0f) || (tm[1] > m[1] + 8.0f);
        if (__any(need)) {   // deferred-max rescale
#pragma unroll
            for (int j = 0; j < 2; ++j) {
                const float mn = fmaxf(m[j], tm[j]);
                const float al = exp2_fast(m[j] - mn);
                m[j] = mn;
                l[j] *= al;
#pragma unroll
                for (int r = 0; r < 4; ++r) {
                    const float ar = __shfl(al, lgrp * 4 + r);
#pragma unroll
                    for (int df = 0; df < 8; ++df) o[j][df][r] *= ar;
                }
            }
        }
        short8 pa[2];
#pragma unroll
        for (int j = 0; j < 2; ++j) {
            const float p0 = exp2_fast(s[j][0][0] - m[j]);
            const float p1 = exp2_fast(s[j][0][1] - m[j]);
            const float p2 = exp2_fast(s[j][0][2] - m[j]);
            const float p3 = exp2_fast(s[j][0][3] - m[j]);
            const float p4 = exp2_fast(s[j][1][0] - m[j]);
            const float p5 = exp2_fast(s[j][1][1] - m[j]);
            const float p6 = exp2_fast(s[j][1][2] - m[j]);
            const float p7 = exp2_fast(s[j][1][3] - m[j]);
            float rs = ((p0 + p1) + (p2 + p3)) + ((p4 + p5) + (p6 + p7));
            rs += __shfl_xor(rs, 16);
            rs += __shfl_xor(rs, 32);
            l[j] += rs;
            pa[j] = pack8(p0, p1, p2, p3, p4, p5, p6, p7);
        }

        // ---- O += P V ----
        __builtin_amdgcn_s_setprio(1);
#pragma unroll
        for (int df = 0; df < 8; ++df) {
            o[0][df] = MFMA16(pa[0], vr[df], o[0][df]);
            o[1][df] = MFMA16(pa[1], vr[df], o[1][df]);
        }
        __builtin_amdgcn_s_setprio(0);
        __syncthreads();
    }

    // ---- state to row form (row = j*16 + lgrp*4 + r) ----
    float mr[2][4], lr_[2][4];
#pragma unroll
    for (int j = 0; j < 2; ++j)
#pragma unroll
        for (int r = 0; r < 4; ++r) {
            mr[j][r]  = __shfl(m[j], lgrp * 4 + r);
            lr_[j][r] = __shfl(l[j], lgrp * 4 + r);
        }

    // ---- write bf16 unnormalized partial + f32 (m,l) ----
#pragma unroll
    for (int j = 0; j < 2; ++j)
#pragma unroll
        for (int df = 0; df < 8; ++df)
#pragma unroll
            for (int r = 0; r < 4; ++r) {
                const int qg = qb + j * 16 + lgrp * 4 + r;
                partO[((size_t)sp * 8192 + qg) * 128 + df * 16 + lrow] = f2bf(o[j][df][r]);
            }
    if (lrow == 0) {
#pragma unroll
        for (int j = 0; j < 2; ++j)
#pragma unroll
            for (int r = 0; r < 4; ++r) {
                const int qg = qb + j * 16 + lgrp * 4 + r;
                partML[((size_t)sp * 8192 + qg) * 2]     = mr[j][r];
                partML[((size_t)sp * 8192 + qg) * 2 + 1] = lr_[j][r];
            }
    }
}

// ---------------------------------------------------------------------------
// Kernel 3: merge 8 kv-split bf16 partials and normalize.
// ---------------------------------------------------------------------------
__global__ __launch_bounds__(256) void merge_kernel(
    const unsigned short* __restrict__ partO, const float* __restrict__ partML,
    float* __restrict__ out)
{
    const int gid = blockIdx.x * 256 + threadIdx.x;   // 0..262143
    const int q = gid >> 5, dc = gid & 31;
    float mv[8], lv[8];
#pragma unroll
    for (int spv = 0; spv < 8; ++spv) {
        mv[spv] = partML[((size_t)spv * 8192 + q) * 2];
        lv[spv] = partML[((size_t)spv * 8192 + q) * 2 + 1];
    }
    float M = mv[0];
#pragma unroll
    for (int spv = 1; spv < 8; ++spv) M = fmaxf(M, mv[spv]);
    float e[8], L = 0.f;
#pragma unroll
    for (int spv = 0; spv < 8; ++spv) { e[spv] = exp2_fast(mv[spv] - M); L += lv[spv] * e[spv]; }
    const float inv = 1.0f / L;
    f32x4 r = (f32x4)0.0f;
#pragma unroll
    for (int spv = 0; spv < 8; ++spv) {
        ushort4_ v = *(const ushort4_*)(partO + ((size_t)spv * 8192 + q) * 128 + dc * 4);
#pragma unroll
        for (int k = 0; k < 4; ++k) r[k] += bf2f(v[k]) * e[spv];
    }
#pragma unroll
    for (int k = 0; k < 4; ++k) r[k] *= inv;
    *(f32x4*)(out + (size_t)q * 128 + dc * 4) = r;
}

extern "C" void kernel_launch(void* const* d_in, const int* in_sizes, int n_in,
                              void* d_out, int out_size, void* d_ws, size_t ws_size,
                              hipStream_t stream)
{
    const float* X  = (const float*)d_in[0];
    const float* Wq = (const float*)d_in[1];
    const float* Wk = (const float*)d_in[2];
    const float* Wv = (const float*)d_in[3];

    char* ws = (char*)d_ws;
    const size_t QS_OFF  = 0;                                   // 2 MiB
    const size_t KB_OFF  = QS_OFF + (size_t)8192 * 128 * 2;     // 2 MiB
    const size_t VT_OFF  = KB_OFF + (size_t)8192 * 128 * 2;     // 2 MiB (V transposed)
    const size_t WB_OFF  = VT_OFF + (size_t)8192 * 128 * 2;     // 768 KiB
    const size_t PO_OFF  = WB_OFF + (size_t)3 * 128 * 1024 * 2; // 8*8192*128 bf16 = 16 MiB
    const size_t PML_OFF = PO_OFF + (size_t)8 * 8192 * 128 * 2; // 8*8192*2 f32 = 512 KiB

    unsigned short* Qs  = (unsigned short*)(ws + QS_OFF);
    unsigned short* Kb  = (unsigned short*)(ws + KB_OFF);
    unsigned short* Vt  = (unsigned short*)(ws + VT_OFF);
    unsigned short* Wb  = (unsigned short*)(ws + WB_OFF);
    unsigned short* partO = (unsigned short*)(ws + PO_OFF);
    float* partML = (float*)(ws + PML_OFF);
    float* out = (float*)d_out;

    wcvt_kernel<<<dim3(128, 3), 256, 0, stream>>>(Wq, Wk, Wv, Wb);
    qkv_kernel<<<dim3(256), 512, 0, stream>>>(X, Wb, Qs, Kb, Vt);
    attn_kernel<<<dim3(512), 256, 0, stream>>>(Qs, Kb, Vt, partO, partML);
    merge_kernel<<<dim3(1024), 256, 0, stream>>>(partO, partML, out);
}

// Round 5
// 191.655 us; speedup vs baseline: 1.3735x; 1.3735x over previous
//
#include <hip/hip_runtime.h>
#include <stdint.h>

typedef __attribute__((ext_vector_type(8))) short short8;       // 8 x bf16
typedef __attribute__((ext_vector_type(4))) float f32x4;
typedef __attribute__((ext_vector_type(4))) unsigned short ushort4_;
typedef __attribute__((ext_vector_type(4))) unsigned int uint4_;

#define MFMA16(a, b, c) __builtin_amdgcn_mfma_f32_16x16x32_bf16((a), (b), (c), 0, 0, 0)

static __device__ __forceinline__ unsigned short f2bf(float f) {
    unsigned u = __float_as_uint(f);
    u += 0x7fffu + ((u >> 16) & 1u);   // RNE
    return (unsigned short)(u >> 16);
}

static __device__ __forceinline__ float bf2f(unsigned short u) {
    return __uint_as_float(((unsigned)u) << 16);
}

static __device__ __forceinline__ float exp2_fast(float x) {
#if __has_builtin(__builtin_amdgcn_exp2f)
    return __builtin_amdgcn_exp2f(x);
#else
    return exp2f(x);
#endif
}

static __device__ __forceinline__ unsigned cvt_pk(float lo, float hi) {
    unsigned r;
    asm("v_cvt_pk_bf16_f32 %0, %1, %2" : "=v"(r) : "v"(lo), "v"(hi));
    return r;
}

static __device__ __forceinline__ short8 pack8(float a0, float a1, float a2, float a3,
                                               float a4, float a5, float a6, float a7) {
    union { uint4_ u; short8 s; } c;
    c.u[0] = cvt_pk(a0, a1); c.u[1] = cvt_pk(a2, a3);
    c.u[2] = cvt_pk(a4, a5); c.u[3] = cvt_pk(a6, a7);
    return c.s;
}

#define GLOAD16(SRC, DSTPTR) __builtin_amdgcn_global_load_lds(                       \
    (const __attribute__((address_space(1))) void*)(SRC),                            \
    (__attribute__((address_space(3))) void*)(DSTPTR), 16, 0, 0)

// ---------------------------------------------------------------------------
// Kernel 0: W (3 heads, f32) -> bf16, contiguous Wb[3][128][1024]
// ---------------------------------------------------------------------------
__global__ __launch_bounds__(256) void wcvt_kernel(
    const float* __restrict__ Wq, const float* __restrict__ Wk, const float* __restrict__ Wv,
    unsigned short* __restrict__ Wb)
{
    const int hd = blockIdx.y;
    const float* W = (hd == 0) ? Wq : ((hd == 1) ? Wk : Wv);
    const int idx = (blockIdx.x * 256 + threadIdx.x) * 4;
    f32x4 v = *(const f32x4*)(W + idx);
    ushort4_ o;
#pragma unroll
    for (int j = 0; j < 4; ++j) o[j] = f2bf(v[j]);
    *(ushort4_*)(Wb + (size_t)hd * 131072 + idx) = o;
}

// ---------------------------------------------------------------------------
// Kernel 1: QKV projection (round-2 verbatim — best measured). M-tile 64,
// 4 waves, grid (128,3); W already bf16.
//   head 0: Q * log2(e)/sqrt(128) -> Qs ; head 1: K -> Kb ; head 2: V -> Vt^T
// ---------------------------------------------------------------------------
__global__ __launch_bounds__(256) void qkv_kernel(
    const float* __restrict__ X, const unsigned short* __restrict__ Wb,
    unsigned short* __restrict__ Qs, unsigned short* __restrict__ Kb, unsigned short* __restrict__ Vt)
{
    __shared__ __align__(16) char lds[24576];   // X bf16 8KB @0, W bf16 16KB @8192
    const int tid  = threadIdx.x;
    const int lane = tid & 63, wid = tid >> 6;
    const int lrow = lane & 15, lgrp = lane >> 4;
    const int m0   = blockIdx.x * 64;
    const int hd   = blockIdx.y;
    const unsigned short* W = Wb + (size_t)hd * 131072;

    f32x4 acc[8];
#pragma unroll
    for (int b = 0; b < 8; b++) acc[b] = (f32x4)0.0f;

    const int xrow = tid >> 2, xseg = tid & 3;   // X: 64 rows, 16 f32/thread
    const int wrow = tid >> 1, whalf = tid & 1;  // W: 128 rows, 64 bf16/thread

    for (int ks = 0; ks < 1024; ks += 64) {
        const float* xsrc = X + (size_t)(m0 + xrow) * 1024 + ks + xseg * 16;
        f32x4 x0 = *(const f32x4*)(xsrc);
        f32x4 x1 = *(const f32x4*)(xsrc + 4);
        f32x4 x2 = *(const f32x4*)(xsrc + 8);
        f32x4 x3 = *(const f32x4*)(xsrc + 12);
        const unsigned short* wsrc = W + (size_t)wrow * 1024 + ks + whalf * 32;
        short8 w0 = *(const short8*)(wsrc);
        short8 w1 = *(const short8*)(wsrc + 8);
        short8 w2 = *(const short8*)(wsrc + 16);
        short8 w3 = *(const short8*)(wsrc + 24);

        const int swx = (xrow & 7) << 4;
        short8 px0 = pack8(x0[0], x0[1], x0[2], x0[3], x1[0], x1[1], x1[2], x1[3]);
        short8 px1 = pack8(x2[0], x2[1], x2[2], x2[3], x3[0], x3[1], x3[2], x3[3]);
        *(short8*)(lds + xrow * 128 + ((xseg * 32)      ^ swx)) = px0;
        *(short8*)(lds + xrow * 128 + ((xseg * 32 + 16) ^ swx)) = px1;
        const int sww = (wrow & 7) << 4;
        *(short8*)(lds + 8192 + wrow * 128 + ((whalf * 64)      ^ sww)) = w0;
        *(short8*)(lds + 8192 + wrow * 128 + ((whalf * 64 + 16) ^ sww)) = w1;
        *(short8*)(lds + 8192 + wrow * 128 + ((whalf * 64 + 32) ^ sww)) = w2;
        *(short8*)(lds + 8192 + wrow * 128 + ((whalf * 64 + 48) ^ sww)) = w3;
        __syncthreads();

#pragma unroll
        for (int kc = 0; kc < 2; ++kc) {
            const int r0 = wid * 16 + lrow;
            const int koff = kc * 64 + lgrp * 16;
            short8 a0 = *(const short8*)(lds + r0 * 128 + (koff ^ ((r0 & 7) << 4)));
#pragma unroll
            for (int cf = 0; cf < 8; ++cf) {
                const int n = cf * 16 + lrow;
                short8 bf = *(const short8*)(lds + 8192 + n * 128 + (koff ^ ((n & 7) << 4)));
                acc[cf] = MFMA16(a0, bf, acc[cf]);
            }
        }
        __syncthreads();
    }

    const float qscale = 0.12752039f;   // log2(e)/sqrt(128)
    if (hd < 2) {
        unsigned short* dst = (hd == 0) ? Qs : Kb;
        const float sc = (hd == 0) ? qscale : 1.0f;
#pragma unroll
        for (int cf = 0; cf < 8; ++cf)
#pragma unroll
            for (int r = 0; r < 4; ++r) {
                const int row = m0 + wid * 16 + lgrp * 4 + r;
                const int col = cf * 16 + lrow;
                dst[(size_t)row * 128 + col] = f2bf(acc[cf][r] * sc);
            }
    } else {
#pragma unroll
        for (int cf = 0; cf < 8; ++cf) {
            const int row0 = m0 + wid * 16 + lgrp * 4;
            const int col  = cf * 16 + lrow;
            ushort4_ v;
#pragma unroll
            for (int r = 0; r < 4; r++) v[r] = f2bf(acc[cf][r]);
            *(ushort4_*)(Vt + (size_t)col * 8192 + row0) = v;
        }
    }
}

// ---------------------------------------------------------------------------
// Kernel 2: flash-attention partial.
// grid 1024 = 128 q-tiles(64 rows) x 8 kv-splits(1024, low bits => sp==XCD).
// Block 256 = 4 waves x 16 q-rows each (halved per-wave state vs r3 =>
// ~125-135 unified regs => 3-4 waves/SIMD). KVBLK=32, K dbuf LDS 16KB via
// global_load_lds w16 (sigma-permuted + XOR-swizzled source, verified r3/r4).
// V direct global->reg. One barrier/iter. NO forced min-waves (r4 lesson).
// Writes bf16 unnormalized partial O + f32 (m,l) per row.
// ---------------------------------------------------------------------------
__global__ __launch_bounds__(256) void attn_kernel(
    const unsigned short* __restrict__ Qs,
    const unsigned short* __restrict__ Kb,
    const unsigned short* __restrict__ Vt,
    unsigned short* __restrict__ partO, float* __restrict__ partML)
{
    __shared__ __align__(16) char lds[16384];   // K dbuf 2 x 8KB
    const int tid = threadIdx.x, lane = tid & 63, wid = tid >> 6;
    const int lrow = lane & 15, lgrp = lane >> 4;
    const int qtile = blockIdx.x >> 3, sp = blockIdx.x & 7;
    const int qb = qtile * 64 + wid * 16;
    const int kvstart = sp * 1024;

    // --- K staging: 2 gloads/thread; LDS linear, source sigma+swizzle ---
    const char* ksrc[2];
    char* kdst[2];
#pragma unroll
    for (int g = 0; g < 2; ++g) {
        const int slot = g * 16 + wid * 4 + (lane >> 4);
        const int krow = ((slot >> 2) & 3) * 8 + ((slot >> 4) & 1) * 4 + (slot & 3);
        const int off = 16 * ((lane & 15) ^ (slot & 15));
        ksrc[g] = (const char*)Kb + (size_t)(kvstart + krow) * 256 + off;
        kdst[g] = lds + g * 4096 + wid * 1024;   // +buf*8192; lane*16 implicit
    }
    // --- V fragment base (direct global, L2-resident) ---
    const char* vbyte = (const char*)Vt + (size_t)lrow * 16384 + (size_t)kvstart * 2 + lgrp * 16;

    // Q fragments: lane holds Q[qb + lrow][c*32 + lgrp*8 ..]
    short8 qf[4];
#pragma unroll
    for (int c = 0; c < 4; ++c)
        qf[c] = *(const short8*)(Qs + (size_t)(qb + lrow) * 128 + c * 32 + lgrp * 8);

    f32x4 o[8];
#pragma unroll
    for (int i = 0; i < 8; ++i) o[i] = (f32x4)0.0f;
    float m = -1e30f, l = 0.0f;

    // prologue: K(0) -> buf 0
#pragma unroll
    for (int g = 0; g < 2; ++g) GLOAD16(ksrc[g], kdst[g]);
    asm volatile("s_waitcnt vmcnt(0)" ::: "memory");
    __syncthreads();

    for (int t = 0; t < 32; ++t) {
        const int buf = t & 1;
        if (t < 31) {   // K(t+1) -> other buffer; in flight across this iter
#pragma unroll
            for (int g = 0; g < 2; ++g)
                GLOAD16(ksrc[g] + (size_t)(t + 1) * 8192, kdst[g] + (buf ^ 1) * 8192);
        }
        short8 vr[8];   // V fragments for tile t
#pragma unroll
        for (int df = 0; df < 8; ++df)
            vr[df] = *(const short8*)(vbyte + (size_t)df * 262144 + t * 64);

        const char* kb = lds + buf * 8192;

        // ---- S^T = K Q (exp2 domain; scale folded into Q) ----
        f32x4 s[2];
        s[0] = (f32x4)0.0f; s[1] = (f32x4)0.0f;
        __builtin_amdgcn_s_setprio(1);
#pragma unroll
        for (int f = 0; f < 2; ++f) {
            const int rbase = (f * 16 + lrow) * 256;
            const int swz = lrow << 4;
#pragma unroll
            for (int c = 0; c < 4; ++c) {
                short8 kf = *(const short8*)(kb + rbase + ((c * 64 + lgrp * 16) ^ swz));
                s[f] = MFMA16(kf, qf[c], s[f]);
            }
        }
        __builtin_amdgcn_s_setprio(0);

        // ---- online softmax: lane owns q=lane&15, kv = 8*lgrp + 4f + r ----
        float t0 = fmaxf(fmaxf(s[0][0], s[0][1]), fmaxf(s[0][2], s[0][3]));
        float t1 = fmaxf(fmaxf(s[1][0], s[1][1]), fmaxf(s[1][2], s[1][3]));
        float tm = fmaxf(t0, t1);
        tm = fmaxf(tm, __shfl_xor(tm, 16));
        tm = fmaxf(tm, __shfl_xor(tm, 32));
        const bool need = (tm > m + 8.0f);
        if (__any(need)) {   // deferred-max rescale
            const float mn = fmaxf(m, tm);
            const float al = exp2_fast(m - mn);
            m = mn;
            l *= al;
#pragma unroll
            for (int r = 0; r < 4; ++r) {
                const float ar = __shfl(al, lgrp * 4 + r);
#pragma unroll
                for (int df = 0; df < 8; ++df) o[df][r] *= ar;
            }
        }
        const float p0 = exp2_fast(s[0][0] - m);
        const float p1 = exp2_fast(s[0][1] - m);
        const float p2 = exp2_fast(s[0][2] - m);
        const float p3 = exp2_fast(s[0][3] - m);
        const float p4 = exp2_fast(s[1][0] - m);
        const float p5 = exp2_fast(s[1][1] - m);
        const float p6 = exp2_fast(s[1][2] - m);
        const float p7 = exp2_fast(s[1][3] - m);
        float rs = ((p0 + p1) + (p2 + p3)) + ((p4 + p5) + (p6 + p7));
        rs += __shfl_xor(rs, 16);
        rs += __shfl_xor(rs, 32);
        l += rs;
        short8 pa = pack8(p0, p1, p2, p3, p4, p5, p6, p7);

        // ---- O += P V ----
        __builtin_amdgcn_s_setprio(1);
#pragma unroll
        for (int df = 0; df < 8; ++df)
            o[df] = MFMA16(pa, vr[df], o[df]);
        __builtin_amdgcn_s_setprio(0);
        __syncthreads();
    }

    // ---- state to row form (row = lgrp*4 + r) ----
    float mr[4], lr_[4];
#pragma unroll
    for (int r = 0; r < 4; ++r) {
        mr[r]  = __shfl(m, lgrp * 4 + r);
        lr_[r] = __shfl(l, lgrp * 4 + r);
    }

    // ---- write bf16 unnormalized partial + f32 (m,l) ----
#pragma unroll
    for (int df = 0; df < 8; ++df)
#pragma unroll
        for (int r = 0; r < 4; ++r) {
            const int qg = qb + lgrp * 4 + r;
            partO[((size_t)sp * 8192 + qg) * 128 + df * 16 + lrow] = f2bf(o[df][r]);
        }
    if (lrow == 0) {
#pragma unroll
        for (int r = 0; r < 4; ++r) {
            const int qg = qb + lgrp * 4 + r;
            partML[((size_t)sp * 8192 + qg) * 2]     = mr[r];
            partML[((size_t)sp * 8192 + qg) * 2 + 1] = lr_[r];
        }
    }
}

// ---------------------------------------------------------------------------
// Kernel 3: merge 8 kv-split bf16 partials and normalize.
// ---------------------------------------------------------------------------
__global__ __launch_bounds__(256) void merge_kernel(
    const unsigned short* __restrict__ partO, const float* __restrict__ partML,
    float* __restrict__ out)
{
    const int gid = blockIdx.x * 256 + threadIdx.x;   // 0..262143
    const int q = gid >> 5, dc = gid & 31;
    float mv[8], lv[8];
#pragma unroll
    for (int spv = 0; spv < 8; ++spv) {
        mv[spv] = partML[((size_t)spv * 8192 + q) * 2];
        lv[spv] = partML[((size_t)spv * 8192 + q) * 2 + 1];
    }
    float M = mv[0];
#pragma unroll
    for (int spv = 1; spv < 8; ++spv) M = fmaxf(M, mv[spv]);
    float e[8], L = 0.f;
#pragma unroll
    for (int spv = 0; spv < 8; ++spv) { e[spv] = exp2_fast(mv[spv] - M); L += lv[spv] * e[spv]; }
    const float inv = 1.0f / L;
    f32x4 r = (f32x4)0.0f;
#pragma unroll
    for (int spv = 0; spv < 8; ++spv) {
        ushort4_ v = *(const ushort4_*)(partO + ((size_t)spv * 8192 + q) * 128 + dc * 4);
#pragma unroll
        for (int k = 0; k < 4; ++k) r[k] += bf2f(v[k]) * e[spv];
    }
#pragma unroll
    for (int k = 0; k < 4; ++k) r[k] *= inv;
    *(f32x4*)(out + (size_t)q * 128 + dc * 4) = r;
}

extern "C" void kernel_launch(void* const* d_in, const int* in_sizes, int n_in,
                              void* d_out, int out_size, void* d_ws, size_t ws_size,
                              hipStream_t stream)
{
    const float* X  = (const float*)d_in[0];
    const float* Wq = (const float*)d_in[1];
    const float* Wk = (const float*)d_in[2];
    const float* Wv = (const float*)d_in[3];

    char* ws = (char*)d_ws;
    const size_t QS_OFF  = 0;                                   // 2 MiB
    const size_t KB_OFF  = QS_OFF + (size_t)8192 * 128 * 2;     // 2 MiB
    const size_t VT_OFF  = KB_OFF + (size_t)8192 * 128 * 2;     // 2 MiB (V transposed)
    const size_t WB_OFF  = VT_OFF + (size_t)8192 * 128 * 2;     // 768 KiB
    const size_t PO_OFF  = WB_OFF + (size_t)3 * 128 * 1024 * 2; // 8*8192*128 bf16 = 16 MiB
    const size_t PML_OFF = PO_OFF + (size_t)8 * 8192 * 128 * 2; // 8*8192*2 f32 = 512 KiB

    unsigned short* Qs  = (unsigned short*)(ws + QS_OFF);
    unsigned short* Kb  = (unsigned short*)(ws + KB_OFF);
    unsigned short* Vt  = (unsigned short*)(ws + VT_OFF);
    unsigned short* Wb  = (unsigned short*)(ws + WB_OFF);
    unsigned short* partO = (unsigned short*)(ws + PO_OFF);
    float* partML = (float*)(ws + PML_OFF);
    float* out = (float*)d_out;

    wcvt_kernel<<<dim3(128, 3), 256, 0, stream>>>(Wq, Wk, Wv, Wb);
    qkv_kernel<<<dim3(128, 3), 256, 0, stream>>>(X, Wb, Qs, Kb, Vt);
    attn_kernel<<<dim3(1024), 256, 0, stream>>>(Qs, Kb, Vt, partO, partML);
    merge_kernel<<<dim3(1024), 256, 0, stream>>>(partO, partML, out);
}

// Round 6
// 134.049 us; speedup vs baseline: 1.9638x; 1.4297x over previous
//
#include <hip/hip_runtime.h>
#include <stdint.h>

typedef __attribute__((ext_vector_type(8))) short short8;       // 8 x bf16
typedef __attribute__((ext_vector_type(4))) float f32x4;
typedef __attribute__((ext_vector_type(4))) unsigned short ushort4_;
typedef __attribute__((ext_vector_type(4))) unsigned int uint4_;

#define MFMA16(a, b, c) __builtin_amdgcn_mfma_f32_16x16x32_bf16((a), (b), (c), 0, 0, 0)

static __device__ __forceinline__ unsigned short f2bf(float f) {
    unsigned u = __float_as_uint(f);
    u += 0x7fffu + ((u >> 16) & 1u);   // RNE
    return (unsigned short)(u >> 16);
}

static __device__ __forceinline__ float bf2f(unsigned short u) {
    return __uint_as_float(((unsigned)u) << 16);
}

static __device__ __forceinline__ float exp2_fast(float x) {
#if __has_builtin(__builtin_amdgcn_exp2f)
    return __builtin_amdgcn_exp2f(x);
#else
    return exp2f(x);
#endif
}

static __device__ __forceinline__ unsigned cvt_pk(float lo, float hi) {
    unsigned r;
    asm("v_cvt_pk_bf16_f32 %0, %1, %2" : "=v"(r) : "v"(lo), "v"(hi));
    return r;
}

static __device__ __forceinline__ short8 pack8(float a0, float a1, float a2, float a3,
                                               float a4, float a5, float a6, float a7) {
    union { uint4_ u; short8 s; } c;
    c.u[0] = cvt_pk(a0, a1); c.u[1] = cvt_pk(a2, a3);
    c.u[2] = cvt_pk(a4, a5); c.u[3] = cvt_pk(a6, a7);
    return c.s;
}

#define GLOAD16(SRC, DSTPTR) __builtin_amdgcn_global_load_lds(                       \
    (const __attribute__((address_space(1))) void*)(SRC),                            \
    (__attribute__((address_space(3))) void*)(DSTPTR), 16, 0, 0)

// ---------------------------------------------------------------------------
// Kernel 0: W (3 heads, f32) -> bf16, contiguous Wb[3][128][1024]
// ---------------------------------------------------------------------------
__global__ __launch_bounds__(256) void wcvt_kernel(
    const float* __restrict__ Wq, const float* __restrict__ Wk, const float* __restrict__ Wv,
    unsigned short* __restrict__ Wb)
{
    const int hd = blockIdx.y;
    const float* W = (hd == 0) ? Wq : ((hd == 1) ? Wk : Wv);
    const int idx = (blockIdx.x * 256 + threadIdx.x) * 4;
    f32x4 v = *(const f32x4*)(W + idx);
    ushort4_ o;
#pragma unroll
    for (int j = 0; j < 4; ++j) o[j] = f2bf(v[j]);
    *(ushort4_*)(Wb + (size_t)hd * 131072 + idx) = o;
}

// ---------------------------------------------------------------------------
// Kernel 1: QKV projection (round-2 verbatim — best measured). M-tile 64,
// 4 waves, grid (128,3); W already bf16.
//   head 0: Q * log2(e)/sqrt(128) -> Qs ; head 1: K -> Kb ; head 2: V -> Vt^T
// ---------------------------------------------------------------------------
__global__ __launch_bounds__(256) void qkv_kernel(
    const float* __restrict__ X, const unsigned short* __restrict__ Wb,
    unsigned short* __restrict__ Qs, unsigned short* __restrict__ Kb, unsigned short* __restrict__ Vt)
{
    __shared__ __align__(16) char lds[24576];   // X bf16 8KB @0, W bf16 16KB @8192
    const int tid  = threadIdx.x;
    const int lane = tid & 63, wid = tid >> 6;
    const int lrow = lane & 15, lgrp = lane >> 4;
    const int m0   = blockIdx.x * 64;
    const int hd   = blockIdx.y;
    const unsigned short* W = Wb + (size_t)hd * 131072;

    f32x4 acc[8];
#pragma unroll
    for (int b = 0; b < 8; b++) acc[b] = (f32x4)0.0f;

    const int xrow = tid >> 2, xseg = tid & 3;   // X: 64 rows, 16 f32/thread
    const int wrow = tid >> 1, whalf = tid & 1;  // W: 128 rows, 64 bf16/thread

    for (int ks = 0; ks < 1024; ks += 64) {
        const float* xsrc = X + (size_t)(m0 + xrow) * 1024 + ks + xseg * 16;
        f32x4 x0 = *(const f32x4*)(xsrc);
        f32x4 x1 = *(const f32x4*)(xsrc + 4);
        f32x4 x2 = *(const f32x4*)(xsrc + 8);
        f32x4 x3 = *(const f32x4*)(xsrc + 12);
        const unsigned short* wsrc = W + (size_t)wrow * 1024 + ks + whalf * 32;
        short8 w0 = *(const short8*)(wsrc);
        short8 w1 = *(const short8*)(wsrc + 8);
        short8 w2 = *(const short8*)(wsrc + 16);
        short8 w3 = *(const short8*)(wsrc + 24);

        const int swx = (xrow & 7) << 4;
        short8 px0 = pack8(x0[0], x0[1], x0[2], x0[3], x1[0], x1[1], x1[2], x1[3]);
        short8 px1 = pack8(x2[0], x2[1], x2[2], x2[3], x3[0], x3[1], x3[2], x3[3]);
        *(short8*)(lds + xrow * 128 + ((xseg * 32)      ^ swx)) = px0;
        *(short8*)(lds + xrow * 128 + ((xseg * 32 + 16) ^ swx)) = px1;
        const int sww = (wrow & 7) << 4;
        *(short8*)(lds + 8192 + wrow * 128 + ((whalf * 64)      ^ sww)) = w0;
        *(short8*)(lds + 8192 + wrow * 128 + ((whalf * 64 + 16) ^ sww)) = w1;
        *(short8*)(lds + 8192 + wrow * 128 + ((whalf * 64 + 32) ^ sww)) = w2;
        *(short8*)(lds + 8192 + wrow * 128 + ((whalf * 64 + 48) ^ sww)) = w3;
        __syncthreads();

#pragma unroll
        for (int kc = 0; kc < 2; ++kc) {
            const int r0 = wid * 16 + lrow;
            const int koff = kc * 64 + lgrp * 16;
            short8 a0 = *(const short8*)(lds + r0 * 128 + (koff ^ ((r0 & 7) << 4)));
#pragma unroll
            for (int cf = 0; cf < 8; ++cf) {
                const int n = cf * 16 + lrow;
                short8 bf = *(const short8*)(lds + 8192 + n * 128 + (koff ^ ((n & 7) << 4)));
                acc[cf] = MFMA16(a0, bf, acc[cf]);
            }
        }
        __syncthreads();
    }

    const float qscale = 0.12752039f;   // log2(e)/sqrt(128)
    if (hd < 2) {
        unsigned short* dst = (hd == 0) ? Qs : Kb;
        const float sc = (hd == 0) ? qscale : 1.0f;
#pragma unroll
        for (int cf = 0; cf < 8; ++cf)
#pragma unroll
            for (int r = 0; r < 4; ++r) {
                const int row = m0 + wid * 16 + lgrp * 4 + r;
                const int col = cf * 16 + lrow;
                dst[(size_t)row * 128 + col] = f2bf(acc[cf][r] * sc);
            }
    } else {
#pragma unroll
        for (int cf = 0; cf < 8; ++cf) {
            const int row0 = m0 + wid * 16 + lgrp * 4;
            const int col  = cf * 16 + lrow;
            ushort4_ v;
#pragma unroll
            for (int r = 0; r < 4; r++) v[r] = f2bf(acc[cf][r]);
            *(ushort4_*)(Vt + (size_t)col * 8192 + row0) = v;
        }
    }
}

// ---------------------------------------------------------------------------
// Kernel 2: flash-attention partial (raw-barrier + counted-vmcnt schedule).
// grid 512 = 64 q-tiles(128 rows) x 8 kv-splits(1024). Block 256 = 4 waves x
// 32 q-rows (j=0,1). KVBLK=32, 32 iters. Shared K tile: dbuf LDS 16KB via
// global_load_lds w16 (sigma-permuted + XOR-swizzled source; verified r3-r5).
// V direct global->reg, issued at iter start (T14).
// Sync per iter: ONE raw s_barrier + vmcnt(8)/vmcnt(2) — never vmcnt(0).
//   issue V(t) -> vmcnt(8) [K(t) retired, in-order] -> s_barrier -> QK ->
//   issue K(t+1) into buf^1 -> softmax -> vmcnt(2) [V(t) done] -> PV.
// K(t+1) write-safety: any wave issuing K(t+1) passed barrier(t), which is
// after every wave's QK(t-1) reads of buf^1 completed (data-dep before PV).
// Writes bf16 unnormalized partial O + f32 (m,l) per row; global 8-way merge.
// ---------------------------------------------------------------------------
__global__ __launch_bounds__(256) void attn_kernel(
    const unsigned short* __restrict__ Qs,
    const unsigned short* __restrict__ Kb,
    const unsigned short* __restrict__ Vt,
    unsigned short* __restrict__ partO, float* __restrict__ partML)
{
    __shared__ __align__(16) char lds[16384];   // K dbuf 2 x 8KB
    const int tid = threadIdx.x, lane = tid & 63, wid = tid >> 6;
    const int lrow = lane & 15, lgrp = lane >> 4;
    const int qtile = blockIdx.x >> 3, sp = blockIdx.x & 7;
    const int qb = qtile * 128 + wid * 32;
    const int kvstart = sp * 1024;

    // --- K staging: 2 gloads/thread; LDS linear, source sigma+swizzle ---
    const char* ksrc[2];
    char* kdst[2];
#pragma unroll
    for (int g = 0; g < 2; ++g) {
        const int slot = g * 16 + wid * 4 + (lane >> 4);
        const int krow = ((slot >> 2) & 3) * 8 + ((slot >> 4) & 1) * 4 + (slot & 3);
        const int off = 16 * ((lane & 15) ^ (slot & 15));
        ksrc[g] = (const char*)Kb + (size_t)(kvstart + krow) * 256 + off;
        kdst[g] = lds + g * 4096 + wid * 1024;   // +buf*8192; lane*16 implicit
    }
    // --- V fragment base (direct global, L2-resident) ---
    const char* vbyte = (const char*)Vt + (size_t)lrow * 16384 + (size_t)kvstart * 2 + lgrp * 16;

    // Q fragments: lane holds Q[qb + j*16 + lrow][c*32 + lgrp*8 ..]
    short8 qf[2][4];
#pragma unroll
    for (int j = 0; j < 2; ++j)
#pragma unroll
        for (int c = 0; c < 4; ++c)
            qf[j][c] = *(const short8*)(Qs + (size_t)(qb + j * 16 + lrow) * 128 + c * 32 + lgrp * 8);

    f32x4 o[2][8];
#pragma unroll
    for (int j = 0; j < 2; ++j)
#pragma unroll
        for (int i = 0; i < 8; ++i) o[j][i] = (f32x4)0.0f;
    float m[2] = { -1e30f, -1e30f }, l[2] = { 0.0f, 0.0f };

    // prologue: K(0) -> buf 0 (single full drain, outside the loop)
#pragma unroll
    for (int g = 0; g < 2; ++g) GLOAD16(ksrc[g], kdst[g]);
    asm volatile("s_waitcnt vmcnt(0)" ::: "memory");
    __builtin_amdgcn_s_barrier();

    for (int t = 0; t < 32; ++t) {
        const int buf = t & 1;

        // ---- issue V(t) FIRST (8 vmem ops; retire after K(t)'s 2) ----
        short8 vr[8];
#pragma unroll
        for (int df = 0; df < 8; ++df)
            vr[df] = *(const short8*)(vbyte + (size_t)df * 262144 + t * 64);

        // K(t) retired (oldest in flight); V(t) may still fly
        asm volatile("s_waitcnt vmcnt(8)" ::: "memory");
        __builtin_amdgcn_s_barrier();

        const char* kb = lds + buf * 8192;

        // ---- S^T = K Q (exp2 domain; scale folded into Q) ----
        f32x4 s[2][2];
        s[0][0] = s[0][1] = s[1][0] = s[1][1] = (f32x4)0.0f;
        __builtin_amdgcn_s_setprio(1);
#pragma unroll
        for (int f = 0; f < 2; ++f) {
            const int rbase = (f * 16 + lrow) * 256;
            const int swz = lrow << 4;
#pragma unroll
            for (int c = 0; c < 4; ++c) {
                short8 kf = *(const short8*)(kb + rbase + ((c * 64 + lgrp * 16) ^ swz));
                s[0][f] = MFMA16(kf, qf[0][c], s[0][f]);
                s[1][f] = MFMA16(kf, qf[1][c], s[1][f]);
            }
        }
        __builtin_amdgcn_s_setprio(0);

        // ---- issue K(t+1) into buf^1 (stays in flight through PV) ----
        if (t < 31) {
#pragma unroll
            for (int g = 0; g < 2; ++g)
                GLOAD16(ksrc[g] + (size_t)(t + 1) * 8192, kdst[g] + (buf ^ 1) * 8192);
        }

        // ---- online softmax: lane owns q=lane&15 (per j), kv = 8*lgrp+4f+r ----
        float tm[2];
#pragma unroll
        for (int j = 0; j < 2; ++j) {
            float t0 = fmaxf(fmaxf(s[j][0][0], s[j][0][1]), fmaxf(s[j][0][2], s[j][0][3]));
            float t1 = fmaxf(fmaxf(s[j][1][0], s[j][1][1]), fmaxf(s[j][1][2], s[j][1][3]));
            float t2 = fmaxf(t0, t1);
            t2 = fmaxf(t2, __shfl_xor(t2, 16));
            t2 = fmaxf(t2, __shfl_xor(t2, 32));
            tm[j] = t2;
        }
        const bool need = (tm[0] > m[0] + 8.0f) || (tm[1] > m[1] + 8.0f);
        if (__any(need)) {   // deferred-max rescale
#pragma unroll
            for (int j = 0; j < 2; ++j) {
                const float mn = fmaxf(m[j], tm[j]);
                const float al = exp2_fast(m[j] - mn);
                m[j] = mn;
                l[j] *= al;
#pragma unroll
                for (int r = 0; r < 4; ++r) {
                    const float ar = __shfl(al, lgrp * 4 + r);
#pragma unroll
                    for (int df = 0; df < 8; ++df) o[j][df][r] *= ar;
                }
            }
        }
        short8 pa[2];
#pragma unroll
        for (int j = 0; j < 2; ++j) {
            const float p0 = exp2_fast(s[j][0][0] - m[j]);
            const float p1 = exp2_fast(s[j][0][1] - m[j]);
            const float p2 = exp2_fast(s[j][0][2] - m[j]);
            const float p3 = exp2_fast(s[j][0][3] - m[j]);
            const float p4 = exp2_fast(s[j][1][0] - m[j]);
            const float p5 = exp2_fast(s[j][1][1] - m[j]);
            const float p6 = exp2_fast(s[j][1][2] - m[j]);
            const float p7 = exp2_fast(s[j][1][3] - m[j]);
            float rs = ((p0 + p1) + (p2 + p3)) + ((p4 + p5) + (p6 + p7));
            rs += __shfl_xor(rs, 16);
            rs += __shfl_xor(rs, 32);
            l[j] += rs;
            pa[j] = pack8(p0, p1, p2, p3, p4, p5, p6, p7);
        }

        // ---- V(t) done; only K(t+1)'s 2 glds may remain in flight ----
        asm volatile("s_waitcnt vmcnt(2)" ::: "memory");

        // ---- O += P V ----
        __builtin_amdgcn_s_setprio(1);
#pragma unroll
        for (int df = 0; df < 8; ++df) {
            o[0][df] = MFMA16(pa[0], vr[df], o[0][df]);
            o[1][df] = MFMA16(pa[1], vr[df], o[1][df]);
        }
        __builtin_amdgcn_s_setprio(0);
        // no trailing barrier: next iter's pre-QK barrier orders buf reuse
    }

    // ---- state to row form (row = j*16 + lgrp*4 + r) ----
    float mr[2][4], lr_[2][4];
#pragma unroll
    for (int j = 0; j < 2; ++j)
#pragma unroll
        for (int r = 0; r < 4; ++r) {
            mr[j][r]  = __shfl(m[j], lgrp * 4 + r);
            lr_[j][r] = __shfl(l[j], lgrp * 4 + r);
        }

    // ---- write bf16 unnormalized partial + f32 (m,l) ----
#pragma unroll
    for (int j = 0; j < 2; ++j)
#pragma unroll
        for (int df = 0; df < 8; ++df)
#pragma unroll
            for (int r = 0; r < 4; ++r) {
                const int qg = qb + j * 16 + lgrp * 4 + r;
                partO[((size_t)sp * 8192 + qg) * 128 + df * 16 + lrow] = f2bf(o[j][df][r]);
            }
    if (lrow == 0) {
#pragma unroll
        for (int j = 0; j < 2; ++j)
#pragma unroll
            for (int r = 0; r < 4; ++r) {
                const int qg = qb + j * 16 + lgrp * 4 + r;
                partML[((size_t)sp * 8192 + qg) * 2]     = mr[j][r];
                partML[((size_t)sp * 8192 + qg) * 2 + 1] = lr_[j][r];
            }
    }
}

// ---------------------------------------------------------------------------
// Kernel 3: merge 8 kv-split bf16 partials and normalize.
// ---------------------------------------------------------------------------
__global__ __launch_bounds__(256) void merge_kernel(
    const unsigned short* __restrict__ partO, const float* __restrict__ partML,
    float* __restrict__ out)
{
    const int gid = blockIdx.x * 256 + threadIdx.x;   // 0..262143
    const int q = gid >> 5, dc = gid & 31;
    float mv[8], lv[8];
#pragma unroll
    for (int spv = 0; spv < 8; ++spv) {
        mv[spv] = partML[((size_t)spv * 8192 + q) * 2];
        lv[spv] = partML[((size_t)spv * 8192 + q) * 2 + 1];
    }
    float M = mv[0];
#pragma unroll
    for (int spv = 1; spv < 8; ++spv) M = fmaxf(M, mv[spv]);
    float e[8], L = 0.f;
#pragma unroll
    for (int spv = 0; spv < 8; ++spv) { e[spv] = exp2_fast(mv[spv] - M); L += lv[spv] * e[spv]; }
    const float inv = 1.0f / L;
    f32x4 r = (f32x4)0.0f;
#pragma unroll
    for (int spv = 0; spv < 8; ++spv) {
        ushort4_ v = *(const ushort4_*)(partO + ((size_t)spv * 8192 + q) * 128 + dc * 4);
#pragma unroll
        for (int k = 0; k < 4; ++k) r[k] += bf2f(v[k]) * e[spv];
    }
#pragma unroll
    for (int k = 0; k < 4; ++k) r[k] *= inv;
    *(f32x4*)(out + (size_t)q * 128 + dc * 4) = r;
}

extern "C" void kernel_launch(void* const* d_in, const int* in_sizes, int n_in,
                              void* d_out, int out_size, void* d_ws, size_t ws_size,
                              hipStream_t stream)
{
    const float* X  = (const float*)d_in[0];
    const float* Wq = (const float*)d_in[1];
    const float* Wk = (const float*)d_in[2];
    const float* Wv = (const float*)d_in[3];

    char* ws = (char*)d_ws;
    const size_t QS_OFF  = 0;                                   // 2 MiB
    const size_t KB_OFF  = QS_OFF + (size_t)8192 * 128 * 2;     // 2 MiB
    const size_t VT_OFF  = KB_OFF + (size_t)8192 * 128 * 2;     // 2 MiB (V transposed)
    const size_t WB_OFF  = VT_OFF + (size_t)8192 * 128 * 2;     // 768 KiB
    const size_t PO_OFF  = WB_OFF + (size_t)3 * 128 * 1024 * 2; // 8*8192*128 bf16 = 16 MiB
    const size_t PML_OFF = PO_OFF + (size_t)8 * 8192 * 128 * 2; // 8*8192*2 f32 = 512 KiB

    unsigned short* Qs  = (unsigned short*)(ws + QS_OFF);
    unsigned short* Kb  = (unsigned short*)(ws + KB_OFF);
    unsigned short* Vt  = (unsigned short*)(ws + VT_OFF);
    unsigned short* Wb  = (unsigned short*)(ws + WB_OFF);
    unsigned short* partO = (unsigned short*)(ws + PO_OFF);
    float* partML = (float*)(ws + PML_OFF);
    float* out = (float*)d_out;

    wcvt_kernel<<<dim3(128, 3), 256, 0, stream>>>(Wq, Wk, Wv, Wb);
    qkv_kernel<<<dim3(128, 3), 256, 0, stream>>>(X, Wb, Qs, Kb, Vt);
    attn_kernel<<<dim3(512), 256, 0, stream>>>(Qs, Kb, Vt, partO, partML);
    merge_kernel<<<dim3(1024), 256, 0, stream>>>(partO, partML, out);
}

// Round 7
// 97.217 us; speedup vs baseline: 2.7078x; 1.3789x over previous
//
#include <hip/hip_runtime.h>
#include <stdint.h>

typedef __attribute__((ext_vector_type(8))) short short8;       // 8 x bf16
typedef __attribute__((ext_vector_type(4))) float f32x4;
typedef __attribute__((ext_vector_type(4))) unsigned short ushort4_;
typedef __attribute__((ext_vector_type(4))) unsigned int uint4_;
typedef __attribute__((ext_vector_type(2))) unsigned int uint2_;

#define MFMA16(a, b, c) __builtin_amdgcn_mfma_f32_16x16x32_bf16((a), (b), (c), 0, 0, 0)

static __device__ __forceinline__ unsigned short f2bf(float f) {
    unsigned u = __float_as_uint(f);
    u += 0x7fffu + ((u >> 16) & 1u);   // RNE
    return (unsigned short)(u >> 16);
}

static __device__ __forceinline__ float bf2f(unsigned short u) {
    return __uint_as_float(((unsigned)u) << 16);
}

static __device__ __forceinline__ float exp2_fast(float x) {
#if __has_builtin(__builtin_amdgcn_exp2f)
    return __builtin_amdgcn_exp2f(x);
#else
    return exp2f(x);
#endif
}

static __device__ __forceinline__ unsigned cvt_pk(float lo, float hi) {
    unsigned r;
    asm("v_cvt_pk_bf16_f32 %0, %1, %2" : "=v"(r) : "v"(lo), "v"(hi));
    return r;
}

static __device__ __forceinline__ short8 pack8(float a0, float a1, float a2, float a3,
                                               float a4, float a5, float a6, float a7) {
    union { uint4_ u; short8 s; } c;
    c.u[0] = cvt_pk(a0, a1); c.u[1] = cvt_pk(a2, a3);
    c.u[2] = cvt_pk(a4, a5); c.u[3] = cvt_pk(a6, a7);
    return c.s;
}

static __device__ __forceinline__ ushort4_ pack4(float a0, float a1, float a2, float a3) {
    union { uint2_ u; ushort4_ s; } c;
    c.u[0] = cvt_pk(a0, a1); c.u[1] = cvt_pk(a2, a3);
    return c.s;
}

#define GLOAD16(SRC, DSTPTR) __builtin_amdgcn_global_load_lds(                       \
    (const __attribute__((address_space(1))) void*)(SRC),                            \
    (__attribute__((address_space(3))) void*)(DSTPTR), 16, 0, 0)

// ---------------------------------------------------------------------------
// Kernel 0: W (3 heads, f32) -> bf16, contiguous Wb[3][128][1024]
// ---------------------------------------------------------------------------
__global__ __launch_bounds__(256) void wcvt_kernel(
    const float* __restrict__ Wq, const float* __restrict__ Wk, const float* __restrict__ Wv,
    unsigned short* __restrict__ Wb)
{
    const int hd = blockIdx.y;
    const float* W = (hd == 0) ? Wq : ((hd == 1) ? Wk : Wv);
    const int idx = (blockIdx.x * 256 + threadIdx.x) * 4;
    f32x4 v = *(const f32x4*)(W + idx);
    ushort4_ o;
#pragma unroll
    for (int j = 0; j < 4; ++j) o[j] = f2bf(v[j]);
    *(ushort4_*)(Wb + (size_t)hd * 131072 + idx) = o;
}

// ---------------------------------------------------------------------------
// Kernel 1: fused QKV (round-4 version). M-tile 32, 512 threads (8 waves x
// 3 cfgs), grid 256 (1 block/CU, 8 waves/CU). X read once (staged bf16 in
// LDS); W bf16 fragments direct from L2 with register double-buffer.
//   head0: Q * log2(e)/sqrt(128) -> Qs ; head1: K -> Kb ; head2: V -> Vt^T
// ---------------------------------------------------------------------------
__global__ __launch_bounds__(512, 2) void qkv_kernel(
    const float* __restrict__ X, const unsigned short* __restrict__ Wb,
    unsigned short* __restrict__ Qs, unsigned short* __restrict__ Kb, unsigned short* __restrict__ Vt)
{
    __shared__ __align__(16) char lds[4096];    // X slice: 32 rows x 64 bf16
    const int tid = threadIdx.x, lane = tid & 63, wid = tid >> 6;
    const int lrow = lane & 15, lgrp = lane >> 4;
    const int m0 = blockIdx.x * 32;

    const int xrow = tid >> 4, xseg = tid & 15;    // 32 rows x 16 segs x 4 f32
    const int xsw = (xrow & 7) << 4;
    const int xoff = xrow * 128 + (((xseg >> 1) * 16) ^ xsw) + (xseg & 1) * 8;
    const float* xbase = X + (size_t)(m0 + xrow) * 1024 + xseg * 4;

    const unsigned short* wp[3];
#pragma unroll
    for (int i = 0; i < 3; ++i) {
        const int cfg = wid * 3 + i;
        wp[i] = Wb + (size_t)(cfg >> 3) * 131072 + (size_t)((cfg & 7) * 16 + lrow) * 1024 + lgrp * 8;
    }

    f32x4 acc[2][3];
#pragma unroll
    for (int mi = 0; mi < 2; ++mi)
#pragma unroll
        for (int i = 0; i < 3; ++i) acc[mi][i] = (f32x4)0.0f;

    f32x4 xr;
    short8 wa[3][2], wb2[3][2];

    // prologue: X(0) -> LDS; W(0) -> wa; X(1) -> xr
    xr = *(const f32x4*)(xbase);
#pragma unroll
    for (int i = 0; i < 3; ++i) {
        wa[i][0] = *(const short8*)(wp[i]);
        wa[i][1] = *(const short8*)(wp[i] + 32);
    }
    *(ushort4_*)(lds + xoff) = pack4(xr[0], xr[1], xr[2], xr[3]);
    xr = *(const f32x4*)(xbase + 64);
    __syncthreads();

#define QKV_STEP(WC, WN, S)                                                          \
    do {                                                                             \
        if ((S) < 15) {                                                              \
            _Pragma("unroll")                                                        \
            for (int i = 0; i < 3; ++i) {                                            \
                WN[i][0] = *(const short8*)(wp[i] + ((S) + 1) * 64);                 \
                WN[i][1] = *(const short8*)(wp[i] + ((S) + 1) * 64 + 32);            \
            }                                                                        \
        }                                                                            \
        __builtin_amdgcn_s_setprio(1);                                               \
        _Pragma("unroll")                                                            \
        for (int kc = 0; kc < 2; ++kc) {                                             \
            short8 a[2];                                                             \
            _Pragma("unroll")                                                        \
            for (int mi = 0; mi < 2; ++mi)                                           \
                a[mi] = *(const short8*)(lds + (mi * 16 + lrow) * 128 +              \
                          ((kc * 64 + lgrp * 16) ^ ((lrow & 7) << 4)));              \
            _Pragma("unroll")                                                        \
            for (int i = 0; i < 3; ++i)                                              \
                _Pragma("unroll")                                                    \
                for (int mi = 0; mi < 2; ++mi)                                       \
                    acc[mi][i] = MFMA16(a[mi], WC[i][kc], acc[mi][i]);               \
        }                                                                            \
        __builtin_amdgcn_s_setprio(0);                                               \
        if ((S) < 15) {                                                              \
            __syncthreads();                                                         \
            *(ushort4_*)(lds + xoff) = pack4(xr[0], xr[1], xr[2], xr[3]);            \
            if ((S) < 14) xr = *(const f32x4*)(xbase + ((S) + 2) * 64);              \
            __syncthreads();                                                         \
        }                                                                            \
    } while (0)

#pragma unroll
    for (int ss = 0; ss < 8; ++ss) {
        QKV_STEP(wa, wb2, 2 * ss);
        QKV_STEP(wb2, wa, 2 * ss + 1);
    }
#undef QKV_STEP

    const float qscale = 0.12752039f;   // log2(e)/sqrt(128)
#pragma unroll
    for (int i = 0; i < 3; ++i) {
        const int cfg = wid * 3 + i;
        const int head = cfg >> 3, cf = cfg & 7;
        if (head < 2) {
            unsigned short* dst = (head == 0) ? Qs : Kb;
            const float sc = (head == 0) ? qscale : 1.0f;
#pragma unroll
            for (int mi = 0; mi < 2; ++mi)
#pragma unroll
                for (int r = 0; r < 4; ++r) {
                    const int row = m0 + mi * 16 + lgrp * 4 + r;
                    dst[(size_t)row * 128 + cf * 16 + lrow] = f2bf(acc[mi][i][r] * sc);
                }
        } else {
#pragma unroll
            for (int mi = 0; mi < 2; ++mi) {
                ushort4_ v;
#pragma unroll
                for (int r = 0; r < 4; ++r) v[r] = f2bf(acc[mi][i][r]);
                *(ushort4_*)(Vt + (size_t)(cf * 16 + lrow) * 8192 + m0 + mi * 16 + lgrp * 4) = v;
            }
        }
    }
}

// ---------------------------------------------------------------------------
// Kernel 2: flash-attention partial, KVBLK=64 (16 iters — amortizes the
// measured ~fixed per-iteration overhead). grid 512 = 64 q-tiles(128 rows) x
// 8 kv-splits(1024; sp==blockIdx&7==XCD -> L2-private K/V slice).
// Block 256 = 4 waves x 32 q-rows (j=0,1). K AND V staged via global_load_lds
// w16 into 64KB dbuf LDS (sigma-permuted / XOR-swizzled SOURCE, linear dest).
// 8 glds issued at iter top into buf^1, ONE __syncthreads per iter (its
// implicit drain retires glds issued ~2000cy earlier). 2 blocks/CU.
// ---------------------------------------------------------------------------
__global__ __launch_bounds__(256) void attn_kernel(
    const unsigned short* __restrict__ Qs,
    const unsigned short* __restrict__ Kb,
    const unsigned short* __restrict__ Vt,
    unsigned short* __restrict__ partO, float* __restrict__ partML)
{
    __shared__ __align__(16) char lds[65536];   // [buf][K 16KB | V 16KB]
    const int tid = threadIdx.x, lane = tid & 63, wid = tid >> 6;
    const int lrow = lane & 15, lgrp = lane >> 4;
    const int qtile = blockIdx.x >> 3, sp = blockIdx.x & 7;
    const int qb = qtile * 128 + wid * 32;
    const int kvstart = sp * 1024;

    // --- K staging: 4 glds/thread; 64 sigma-permuted rows, swizzled source ---
    const char* ksrc[4];
    int kdoff[4];
#pragma unroll
    for (int g = 0; g < 4; ++g) {
        const int slot = g * 16 + wid * 4 + lgrp;            // 0..63
        const int krow = (slot & 32) | (((slot >> 2) & 3) << 3)
                       | (((slot >> 4) & 1) << 2) | (slot & 3);
        ksrc[g] = (const char*)Kb + (size_t)(kvstart + krow) * 256
                + 16 * (lrow ^ (slot & 15));
        kdoff[g] = g * 4096 + wid * 1024;                    // + buf*32768
    }
    // --- V staging: 4 glds/thread; tile [128 d][128B], row-XOR swizzle ---
    const char* vsrc[4];
    int vdoff[4];
#pragma unroll
    for (int g = 0; g < 4; ++g) {
        const int drow = (wid * 4 + g) * 8 + (lane >> 3);    // 0..127
        vsrc[g] = (const char*)Vt + (size_t)drow * 16384 + (size_t)kvstart * 2
                + (((lane & 7) * 16) ^ ((drow & 7) << 4));
        vdoff[g] = (wid * 4 + g) * 1024;                     // + buf*32768 + 16384
    }

    // Q fragments: lane holds Q[qb + j*16 + lrow][c*32 + lgrp*8 ..]
    short8 qf[2][4];
#pragma unroll
    for (int j = 0; j < 2; ++j)
#pragma unroll
        for (int c = 0; c < 4; ++c)
            qf[j][c] = *(const short8*)(Qs + (size_t)(qb + j * 16 + lrow) * 128 + c * 32 + lgrp * 8);

    f32x4 o[2][8];
#pragma unroll
    for (int j = 0; j < 2; ++j)
#pragma unroll
        for (int i = 0; i < 8; ++i) o[j][i] = (f32x4)0.0f;
    float m[2] = { -1e30f, -1e30f }, l[2] = { 0.0f, 0.0f };

    // prologue: tile 0 -> buf 0
#pragma unroll
    for (int g = 0; g < 4; ++g) GLOAD16(ksrc[g], lds + kdoff[g]);
#pragma unroll
    for (int g = 0; g < 4; ++g) GLOAD16(vsrc[g], lds + 16384 + vdoff[g]);
    __syncthreads();

    for (int t = 0; t < 16; ++t) {
        const int buf = t & 1;
        const char* kb = lds + buf * 32768;
        const char* vb = kb + 16384;

        // ---- issue next tile's 8 glds into buf^1 (overlap this iter) ----
        if (t < 15) {
            char* nk = lds + (buf ^ 1) * 32768;
#pragma unroll
            for (int g = 0; g < 4; ++g)
                GLOAD16(ksrc[g] + (size_t)(t + 1) * 16384, nk + kdoff[g]);
#pragma unroll
            for (int g = 0; g < 4; ++g)
                GLOAD16(vsrc[g] + (size_t)(t + 1) * 128, nk + 16384 + vdoff[g]);
        }

        // ---- S^T = K Q over 64 kv (exp2 domain; scale folded into Q) ----
        f32x4 s[2][4];
#pragma unroll
        for (int f = 0; f < 4; ++f) { s[0][f] = (f32x4)0.0f; s[1][f] = (f32x4)0.0f; }
        __builtin_amdgcn_s_setprio(1);
#pragma unroll
        for (int f = 0; f < 4; ++f) {
            const int rbase = (f * 16 + lrow) * 256;
            const int swz = lrow << 4;
#pragma unroll
            for (int c = 0; c < 4; ++c) {
                short8 kf = *(const short8*)(kb + rbase + ((c * 64 + lgrp * 16) ^ swz));
                s[0][f] = MFMA16(kf, qf[0][c], s[0][f]);
                s[1][f] = MFMA16(kf, qf[1][c], s[1][f]);
            }
        }
        __builtin_amdgcn_s_setprio(0);

        // ---- online softmax: lane owns q=lane&15 (per j);
        //      kv = (f>>1)*32 + 8*lgrp + 4*(f&1) + r ----
        float tm[2];
#pragma unroll
        for (int j = 0; j < 2; ++j) {
            float a0 = fmaxf(fmaxf(s[j][0][0], s[j][0][1]), fmaxf(s[j][0][2], s[j][0][3]));
            float a1 = fmaxf(fmaxf(s[j][1][0], s[j][1][1]), fmaxf(s[j][1][2], s[j][1][3]));
            float a2 = fmaxf(fmaxf(s[j][2][0], s[j][2][1]), fmaxf(s[j][2][2], s[j][2][3]));
            float a3 = fmaxf(fmaxf(s[j][3][0], s[j][3][1]), fmaxf(s[j][3][2], s[j][3][3]));
            float t2 = fmaxf(fmaxf(a0, a1), fmaxf(a2, a3));
            t2 = fmaxf(t2, __shfl_xor(t2, 16));
            t2 = fmaxf(t2, __shfl_xor(t2, 32));
            tm[j] = t2;
        }
        const bool need = (tm[0] > m[0] + 8.0f) || (tm[1] > m[1] + 8.0f);
        if (__any(need)) {   // deferred-max rescale
#pragma unroll
            for (int j = 0; j < 2; ++j) {
                const float mn = fmaxf(m[j], tm[j]);
                const float al = exp2_fast(m[j] - mn);
                m[j] = mn;
                l[j] *= al;
#pragma unroll
                for (int r = 0; r < 4; ++r) {
                    const float ar = __shfl(al, lgrp * 4 + r);
#pragma unroll
                    for (int df = 0; df < 8; ++df) o[j][df][r] *= ar;
                }
            }
        }
        short8 pa[2][2];
#pragma unroll
        for (int j = 0; j < 2; ++j) {
            float rs = 0.0f;
#pragma unroll
            for (int f = 0; f < 4; ++f)
#pragma unroll
                for (int r = 0; r < 4; ++r) {
                    const float p = exp2_fast(s[j][f][r] - m[j]);
                    s[j][f][r] = p;
                    rs += p;
                }
            rs += __shfl_xor(rs, 16);
            rs += __shfl_xor(rs, 32);
            l[j] += rs;
            pa[j][0] = pack8(s[j][0][0], s[j][0][1], s[j][0][2], s[j][0][3],
                             s[j][1][0], s[j][1][1], s[j][1][2], s[j][1][3]);
            pa[j][1] = pack8(s[j][2][0], s[j][2][1], s[j][2][2], s[j][2][3],
                             s[j][3][0], s[j][3][1], s[j][3][2], s[j][3][3]);
        }

        // ---- O += P V (V from LDS; 16 reads, 32 MFMA) ----
        __builtin_amdgcn_s_setprio(1);
#pragma unroll
        for (int ks = 0; ks < 2; ++ks) {
#pragma unroll
            for (int df = 0; df < 8; ++df) {
                const int d = df * 16 + lrow;
                short8 vf = *(const short8*)(vb + d * 128 +
                              ((ks * 64 + lgrp * 16) ^ ((d & 7) << 4)));
                o[0][df] = MFMA16(pa[0][ks], vf, o[0][df]);
                o[1][df] = MFMA16(pa[1][ks], vf, o[1][df]);
            }
        }
        __builtin_amdgcn_s_setprio(0);

        __syncthreads();   // drains this wave's glds; orders buf swap
    }

    // ---- state to row form (row = j*16 + lgrp*4 + r) ----
    float mr[2][4], lr_[2][4];
#pragma unroll
    for (int j = 0; j < 2; ++j)
#pragma unroll
        for (int r = 0; r < 4; ++r) {
            mr[j][r]  = __shfl(m[j], lgrp * 4 + r);
            lr_[j][r] = __shfl(l[j], lgrp * 4 + r);
        }

    // ---- write bf16 unnormalized partial + f32 (m,l) ----
#pragma unroll
    for (int j = 0; j < 2; ++j)
#pragma unroll
        for (int df = 0; df < 8; ++df)
#pragma unroll
            for (int r = 0; r < 4; ++r) {
                const int qg = qb + j * 16 + lgrp * 4 + r;
                partO[((size_t)sp * 8192 + qg) * 128 + df * 16 + lrow] = f2bf(o[j][df][r]);
            }
    if (lrow == 0) {
#pragma unroll
        for (int j = 0; j < 2; ++j)
#pragma unroll
            for (int r = 0; r < 4; ++r) {
                const int qg = qb + j * 16 + lgrp * 4 + r;
                partML[((size_t)sp * 8192 + qg) * 2]     = mr[j][r];
                partML[((size_t)sp * 8192 + qg) * 2 + 1] = lr_[j][r];
            }
    }
}

// ---------------------------------------------------------------------------
// Kernel 3: merge 8 kv-split bf16 partials and normalize.
// ---------------------------------------------------------------------------
__global__ __launch_bounds__(256) void merge_kernel(
    const unsigned short* __restrict__ partO, const float* __restrict__ partML,
    float* __restrict__ out)
{
    const int gid = blockIdx.x * 256 + threadIdx.x;   // 0..262143
    const int q = gid >> 5, dc = gid & 31;
    float mv[8], lv[8];
#pragma unroll
    for (int spv = 0; spv < 8; ++spv) {
        mv[spv] = partML[((size_t)spv * 8192 + q) * 2];
        lv[spv] = partML[((size_t)spv * 8192 + q) * 2 + 1];
    }
    float M = mv[0];
#pragma unroll
    for (int spv = 1; spv < 8; ++spv) M = fmaxf(M, mv[spv]);
    float e[8], L = 0.f;
#pragma unroll
    for (int spv = 0; spv < 8; ++spv) { e[spv] = exp2_fast(mv[spv] - M); L += lv[spv] * e[spv]; }
    const float inv = 1.0f / L;
    f32x4 r = (f32x4)0.0f;
#pragma unroll
    for (int spv = 0; spv < 8; ++spv) {
        ushort4_ v = *(const ushort4_*)(partO + ((size_t)spv * 8192 + q) * 128 + dc * 4);
#pragma unroll
        for (int k = 0; k < 4; ++k) r[k] += bf2f(v[k]) * e[spv];
    }
#pragma unroll
    for (int k = 0; k < 4; ++k) r[k] *= inv;
    *(f32x4*)(out + (size_t)q * 128 + dc * 4) = r;
}

extern "C" void kernel_launch(void* const* d_in, const int* in_sizes, int n_in,
                              void* d_out, int out_size, void* d_ws, size_t ws_size,
                              hipStream_t stream)
{
    const float* X  = (const float*)d_in[0];
    const float* Wq = (const float*)d_in[1];
    const float* Wk = (const float*)d_in[2];
    const float* Wv = (const float*)d_in[3];

    char* ws = (char*)d_ws;
    const size_t QS_OFF  = 0;                                   // 2 MiB
    const size_t KB_OFF  = QS_OFF + (size_t)8192 * 128 * 2;     // 2 MiB
    const size_t VT_OFF  = KB_OFF + (size_t)8192 * 128 * 2;     // 2 MiB (V transposed)
    const size_t WB_OFF  = VT_OFF + (size_t)8192 * 128 * 2;     // 768 KiB
    const size_t PO_OFF  = WB_OFF + (size_t)3 * 128 * 1024 * 2; // 8*8192*128 bf16 = 16 MiB
    const size_t PML_OFF = PO_OFF + (size_t)8 * 8192 * 128 * 2; // 8*8192*2 f32 = 512 KiB

    unsigned short* Qs  = (unsigned short*)(ws + QS_OFF);
    unsigned short* Kb  = (unsigned short*)(ws + KB_OFF);
    unsigned short* Vt  = (unsigned short*)(ws + VT_OFF);
    unsigned short* Wb  = (unsigned short*)(ws + WB_OFF);
    unsigned short* partO = (unsigned short*)(ws + PO_OFF);
    float* partML = (float*)(ws + PML_OFF);
    float* out = (float*)d_out;

    wcvt_kernel<<<dim3(128, 3), 256, 0, stream>>>(Wq, Wk, Wv, Wb);
    qkv_kernel<<<dim3(256), 512, 0, stream>>>(X, Wb, Qs, Kb, Vt);
    attn_kernel<<<dim3(512), 256, 0, stream>>>(Qs, Kb, Vt, partO, partML);
    merge_kernel<<<dim3(1024), 256, 0, stream>>>(partO, partML, out);
}

// Round 9
// 91.521 us; speedup vs baseline: 2.8763x; 1.0622x over previous
//
#include <hip/hip_runtime.h>
#include <stdint.h>

typedef __attribute__((ext_vector_type(8))) short short8;       // 8 x bf16
typedef __attribute__((ext_vector_type(4))) float f32x4;
typedef __attribute__((ext_vector_type(4))) unsigned short ushort4_;
typedef __attribute__((ext_vector_type(4))) unsigned int uint4_;

#define MFMA16(a, b, c) __builtin_amdgcn_mfma_f32_16x16x32_bf16((a), (b), (c), 0, 0, 0)

static __device__ __forceinline__ unsigned short f2bf(float f) {
    unsigned u = __float_as_uint(f);
    u += 0x7fffu + ((u >> 16) & 1u);   // RNE
    return (unsigned short)(u >> 16);
}

static __device__ __forceinline__ float bf2f(unsigned short u) {
    return __uint_as_float(((unsigned)u) << 16);
}

static __device__ __forceinline__ float exp2_fast(float x) {
#if __has_builtin(__builtin_amdgcn_exp2f)
    return __builtin_amdgcn_exp2f(x);
#else
    return exp2f(x);
#endif
}

static __device__ __forceinline__ unsigned cvt_pk(float lo, float hi) {
    unsigned r;
    asm("v_cvt_pk_bf16_f32 %0, %1, %2" : "=v"(r) : "v"(lo), "v"(hi));
    return r;
}

static __device__ __forceinline__ short8 pack8(float a0, float a1, float a2, float a3,
                                               float a4, float a5, float a6, float a7) {
    union { uint4_ u; short8 s; } c;
    c.u[0] = cvt_pk(a0, a1); c.u[1] = cvt_pk(a2, a3);
    c.u[2] = cvt_pk(a4, a5); c.u[3] = cvt_pk(a6, a7);
    return c.s;
}

#define GLOAD16(SRC, DSTPTR) __builtin_amdgcn_global_load_lds(                       \
    (const __attribute__((address_space(1))) void*)(SRC),                            \
    (__attribute__((address_space(3))) void*)(DSTPTR), 16, 0, 0)

// ---------------------------------------------------------------------------
// Kernel 0: W (3 heads, f32) -> bf16, contiguous Wb[3][128][1024]
// ---------------------------------------------------------------------------
__global__ __launch_bounds__(256) void wcvt_kernel(
    const float* __restrict__ Wq, const float* __restrict__ Wk, const float* __restrict__ Wv,
    unsigned short* __restrict__ Wb)
{
    const int hd = blockIdx.y;
    const float* W = (hd == 0) ? Wq : ((hd == 1) ? Wk : Wv);
    const int idx = (blockIdx.x * 256 + threadIdx.x) * 4;
    f32x4 v = *(const f32x4*)(W + idx);
    ushort4_ o;
#pragma unroll
    for (int j = 0; j < 4; ++j) o[j] = f2bf(v[j]);
    *(ushort4_*)(Wb + (size_t)hd * 131072 + idx) = o;
}

// ---------------------------------------------------------------------------
// Kernel 1: QKV projection. Per-head blocks: grid (128, 3), M-tile 64,
// 4 waves x 16 rows. K-step 64, 16 steps, ONE __syncthreads per step.
// W staged via global_load_lds w16 (XOR-swizzled source, linear dest);
// X f32 reg-staged (T14: loads at top, pack+ds_write after compute).
// LDS 48KB -> 3 blocks/CU.
//   head0: Q * log2(e)/sqrt(128) -> Qs ; head1: K -> Kb ; head2: V -> Vt^T
// ---------------------------------------------------------------------------
__global__ __launch_bounds__(256) void qkv_kernel(
    const float* __restrict__ X, const unsigned short* __restrict__ Wb,
    unsigned short* __restrict__ Qs, unsigned short* __restrict__ Kb, unsigned short* __restrict__ Vt)
{
    __shared__ __align__(16) char lds[49152];   // X dbuf 2x8KB @0; W dbuf 2x16KB @16384
    const int tid  = threadIdx.x;
    const int lane = tid & 63, wid = tid >> 6;
    const int lrow = lane & 15, lgrp = lane >> 4;
    const int m0   = blockIdx.x * 64;
    const int hd   = blockIdx.y;
    const unsigned short* W = Wb + (size_t)hd * 131072;

    // --- W staging: 4 glds/thread; tile [128 rows][128B], swizzled source ---
    const char* wsrc[4];
    int wdoff[4];
#pragma unroll
    for (int g = 0; g < 4; ++g) {
        const int slot = g * 256 + tid;          // 0..1023
        const int row = slot >> 3, c16 = slot & 7;
        wsrc[g] = (const char*)(W + (size_t)row * 1024) + 16 * (c16 ^ (row & 7));
        wdoff[g] = g * 4096 + wid * 1024;        // wave-linear dest (lane*16 implicit)
    }
    // --- X staging: 16 f32/thread -> bf16 pack -> 2 swizzled ds_writes ---
    const int xrow = tid >> 2, xseg = tid & 3;   // 64 rows x 4 segs x 16 f32
    const float* xbase = X + (size_t)(m0 + xrow) * 1024 + xseg * 16;
    const int xsw = (xrow & 7) << 4;
    const int xwoff0 = xrow * 128 + (((xseg * 2)     * 16) ^ xsw);
    const int xwoff1 = xrow * 128 + (((xseg * 2 + 1) * 16) ^ xsw);

    f32x4 acc[8];
#pragma unroll
    for (int b = 0; b < 8; b++) acc[b] = (f32x4)0.0f;

    // prologue: W(0) -> Wbuf0; X(0) -> Xbuf0
#pragma unroll
    for (int g = 0; g < 4; ++g) GLOAD16(wsrc[g], lds + 16384 + wdoff[g]);
    {
        f32x4 x0 = *(const f32x4*)(xbase);
        f32x4 x1 = *(const f32x4*)(xbase + 4);
        f32x4 x2 = *(const f32x4*)(xbase + 8);
        f32x4 x3 = *(const f32x4*)(xbase + 12);
        *(short8*)(lds + xwoff0) = pack8(x0[0], x0[1], x0[2], x0[3], x1[0], x1[1], x1[2], x1[3]);
        *(short8*)(lds + xwoff1) = pack8(x2[0], x2[1], x2[2], x2[3], x3[0], x3[1], x3[2], x3[3]);
    }
    __syncthreads();

    for (int ks = 0; ks < 16; ++ks) {
        const int buf = ks & 1;
        f32x4 nx0, nx1, nx2, nx3;
        if (ks < 15) {   // issue next step's W glds + X reg loads (fly during compute)
#pragma unroll
            for (int g = 0; g < 4; ++g)
                GLOAD16(wsrc[g] + (size_t)(ks + 1) * 128, lds + 16384 + (buf ^ 1) * 16384 + wdoff[g]);
            nx0 = *(const f32x4*)(xbase + (ks + 1) * 64);
            nx1 = *(const f32x4*)(xbase + (ks + 1) * 64 + 4);
            nx2 = *(const f32x4*)(xbase + (ks + 1) * 64 + 8);
            nx3 = *(const f32x4*)(xbase + (ks + 1) * 64 + 12);
        }
        const char* xb  = lds + buf * 8192;
        const char* wbl = lds + 16384 + buf * 16384;
        __builtin_amdgcn_s_setprio(1);
#pragma unroll
        for (int kc = 0; kc < 2; ++kc) {
            const int arow = wid * 16 + lrow;
            const int koff = (kc * 64 + lgrp * 16) ^ ((lrow & 7) << 4);
            short8 a = *(const short8*)(xb + arow * 128 + koff);
#pragma unroll
            for (int cf = 0; cf < 8; ++cf) {
                const int n = cf * 16 + lrow;
                short8 b = *(const short8*)(wbl + n * 128 + koff);
                acc[cf] = MFMA16(a, b, acc[cf]);
            }
        }
        __builtin_amdgcn_s_setprio(0);
        if (ks < 15) {   // pack + write X(ks+1) into buf^1 (read-safe: barrier(ks-1..) passed)
            *(short8*)(lds + (buf ^ 1) * 8192 + xwoff0) =
                pack8(nx0[0], nx0[1], nx0[2], nx0[3], nx1[0], nx1[1], nx1[2], nx1[3]);
            *(short8*)(lds + (buf ^ 1) * 8192 + xwoff1) =
                pack8(nx2[0], nx2[1], nx2[2], nx2[3], nx3[0], nx3[1], nx3[2], nx3[3]);
        }
        __syncthreads();
    }

    const float qscale = 0.12752039f;   // log2(e)/sqrt(128)
    if (hd < 2) {
        unsigned short* dst = (hd == 0) ? Qs : Kb;
        const float sc = (hd == 0) ? qscale : 1.0f;
#pragma unroll
        for (int cf = 0; cf < 8; ++cf)
#pragma unroll
            for (int r = 0; r < 4; ++r) {
                const int row = m0 + wid * 16 + lgrp * 4 + r;
                const int col = cf * 16 + lrow;
                dst[(size_t)row * 128 + col] = f2bf(acc[cf][r] * sc);
            }
    } else {
#pragma unroll
        for (int cf = 0; cf < 8; ++cf) {
            const int row0 = m0 + wid * 16 + lgrp * 4;
            const int col  = cf * 16 + lrow;
            ushort4_ v;
#pragma unroll
            for (int r = 0; r < 4; r++) v[r] = f2bf(acc[cf][r]);
            *(ushort4_*)(Vt + (size_t)col * 8192 + row0) = v;
        }
    }
}

// ---------------------------------------------------------------------------
// Kernel 2: flash-attention partial, KVBLK=64, SOFTWARE-PIPELINED:
//   iter t: barrier -> issue K(t+2),V(t+1) -> QK(t+1) [MFMA] ->
//           softmax(t) [VALU, overlaps] -> PV(t).
// Two S-sets (sA/sB) statically swapped via even/odd bodies; 4 x 16KB LDS
// buffers (Kb0,Kb1,Vb0,Vb1) individually phased. Every gld flies one full
// iteration before its barrier drain. grid 512 = 64 q-tiles(128) x 8 sp.
// Block 256 = 4 waves x 32 q. LDS 64KB -> 2 blocks/CU.
// r9 FIX: odd-half K prefetch guard was (e < 12), dropping K15 -> QK(15)
// read stale K13 (absmax 4.5e-3). Now (e < 14): stages K3..K15 exactly.
// ---------------------------------------------------------------------------
__global__ __launch_bounds__(256) void attn_kernel(
    const unsigned short* __restrict__ Qs,
    const unsigned short* __restrict__ Kb,
    const unsigned short* __restrict__ Vt,
    unsigned short* __restrict__ partO, float* __restrict__ partML)
{
    __shared__ __align__(16) char lds[65536];   // Kb0@0 Kb1@16K Vb0@32K Vb1@48K
    const int tid = threadIdx.x, lane = tid & 63, wid = tid >> 6;
    const int lrow = lane & 15, lgrp = lane >> 4;
    const int qtile = blockIdx.x >> 3, sp = blockIdx.x & 7;
    const int qb = qtile * 128 + wid * 32;
    const int kvstart = sp * 1024;

    // --- K staging: 4 glds/thread; 64 sigma-permuted rows, swizzled source ---
    const char* ksrc[4];
    int kdoff[4];
#pragma unroll
    for (int g = 0; g < 4; ++g) {
        const int slot = g * 16 + wid * 4 + lgrp;            // 0..63
        const int krow = (slot & 32) | (((slot >> 2) & 3) << 3)
                       | (((slot >> 4) & 1) << 2) | (slot & 3);
        ksrc[g] = (const char*)Kb + (size_t)(kvstart + krow) * 256
                + 16 * (lrow ^ (slot & 15));
        kdoff[g] = g * 4096 + wid * 1024;
    }
    // --- V staging: 4 glds/thread; tile [128 d][128B], row-XOR swizzle ---
    const char* vsrc[4];
    int vdoff[4];
#pragma unroll
    for (int g = 0; g < 4; ++g) {
        const int drow = (wid * 4 + g) * 8 + (lane >> 3);    // 0..127
        vsrc[g] = (const char*)Vt + (size_t)drow * 16384 + (size_t)kvstart * 2
                + (((lane & 7) * 16) ^ ((drow & 7) << 4));
        vdoff[g] = (wid * 4 + g) * 1024;
    }

    // Q fragments: lane holds Q[qb + j*16 + lrow][c*32 + lgrp*8 ..]
    short8 qf[2][4];
#pragma unroll
    for (int j = 0; j < 2; ++j)
#pragma unroll
        for (int c = 0; c < 4; ++c)
            qf[j][c] = *(const short8*)(Qs + (size_t)(qb + j * 16 + lrow) * 128 + c * 32 + lgrp * 8);

    f32x4 o[2][8];
#pragma unroll
    for (int j = 0; j < 2; ++j)
#pragma unroll
        for (int i = 0; i < 8; ++i) o[j][i] = (f32x4)0.0f;
    float m[2] = { -1e30f, -1e30f }, l[2] = { 0.0f, 0.0f };
    f32x4 sA[2][4], sB[2][4];

#define STG_K(TT, DSTBASE) do {                                                      \
    _Pragma("unroll")                                                                \
    for (int g = 0; g < 4; ++g)                                                      \
        GLOAD16(ksrc[g] + (size_t)(TT) * 16384, (DSTBASE) + kdoff[g]);               \
} while (0)

#define STG_V(TT, DSTBASE) do {                                                      \
    _Pragma("unroll")                                                                \
    for (int g = 0; g < 4; ++g)                                                      \
        GLOAD16(vsrc[g] + (size_t)(TT) * 128, (DSTBASE) + vdoff[g]);                 \
} while (0)

#define QK_TILE(S, KBASE) do {                                                       \
    _Pragma("unroll")                                                                \
    for (int f = 0; f < 4; ++f) { S[0][f] = (f32x4)0.0f; S[1][f] = (f32x4)0.0f; }    \
    __builtin_amdgcn_s_setprio(1);                                                   \
    _Pragma("unroll")                                                                \
    for (int f = 0; f < 4; ++f) {                                                    \
        const int rbase = (f * 16 + lrow) * 256;                                     \
        const int swz = lrow << 4;                                                   \
        _Pragma("unroll")                                                            \
        for (int c = 0; c < 4; ++c) {                                                \
            short8 kf = *(const short8*)((KBASE) + rbase + ((c * 64 + lgrp * 16) ^ swz)); \
            S[0][f] = MFMA16(kf, qf[0][c], S[0][f]);                                 \
            S[1][f] = MFMA16(kf, qf[1][c], S[1][f]);                                 \
        }                                                                            \
    }                                                                                \
    __builtin_amdgcn_s_setprio(0);                                                   \
} while (0)

#define SM_PV(S, VBASE) do {                                                         \
    float tm[2];                                                                     \
    _Pragma("unroll")                                                                \
    for (int j = 0; j < 2; ++j) {                                                    \
        float a0 = fmaxf(fmaxf(S[j][0][0], S[j][0][1]), fmaxf(S[j][0][2], S[j][0][3])); \
        float a1 = fmaxf(fmaxf(S[j][1][0], S[j][1][1]), fmaxf(S[j][1][2], S[j][1][3])); \
        float a2 = fmaxf(fmaxf(S[j][2][0], S[j][2][1]), fmaxf(S[j][2][2], S[j][2][3])); \
        float a3 = fmaxf(fmaxf(S[j][3][0], S[j][3][1]), fmaxf(S[j][3][2], S[j][3][3])); \
        float t2 = fmaxf(fmaxf(a0, a1), fmaxf(a2, a3));                              \
        t2 = fmaxf(t2, __shfl_xor(t2, 16));                                          \
        t2 = fmaxf(t2, __shfl_xor(t2, 32));                                          \
        tm[j] = t2;                                                                  \
    }                                                                                \
    const bool need = (tm[0] > m[0] + 8.0f) || (tm[1] > m[1] + 8.0f);                \
    if (__any(need)) {                                                               \
        _Pragma("unroll")                                                            \
        for (int j = 0; j < 2; ++j) {                                                \
            const float mn = fmaxf(m[j], tm[j]);                                     \
            const float al = exp2_fast(m[j] - mn);                                   \
            m[j] = mn; l[j] *= al;                                                   \
            _Pragma("unroll")                                                        \
            for (int r = 0; r < 4; ++r) {                                            \
                const float ar = __shfl(al, lgrp * 4 + r);                           \
                _Pragma("unroll")                                                    \
                for (int df = 0; df < 8; ++df) o[j][df][r] *= ar;                    \
            }                                                                        \
        }                                                                            \
    }                                                                                \
    short8 pa[2][2];                                                                 \
    _Pragma("unroll")                                                                \
    for (int j = 0; j < 2; ++j) {                                                    \
        float rs = 0.0f;                                                             \
        _Pragma("unroll")                                                            \
        for (int f = 0; f < 4; ++f)                                                  \
            _Pragma("unroll")                                                        \
            for (int r = 0; r < 4; ++r) {                                            \
                const float p = exp2_fast(S[j][f][r] - m[j]);                        \
                S[j][f][r] = p; rs += p;                                             \
            }                                                                        \
        rs += __shfl_xor(rs, 16);                                                    \
        rs += __shfl_xor(rs, 32);                                                    \
        l[j] += rs;                                                                  \
        pa[j][0] = pack8(S[j][0][0], S[j][0][1], S[j][0][2], S[j][0][3],             \
                         S[j][1][0], S[j][1][1], S[j][1][2], S[j][1][3]);            \
        pa[j][1] = pack8(S[j][2][0], S[j][2][1], S[j][2][2], S[j][2][3],             \
                         S[j][3][0], S[j][3][1], S[j][3][2], S[j][3][3]);            \
    }                                                                                \
    __builtin_amdgcn_s_setprio(1);                                                   \
    _Pragma("unroll")                                                                \
    for (int ks = 0; ks < 2; ++ks)                                                   \
        _Pragma("unroll")                                                            \
        for (int df = 0; df < 8; ++df) {                                             \
            const int d = df * 16 + lrow;                                            \
            short8 vf = *(const short8*)((VBASE) + d * 128 +                         \
                          ((ks * 64 + lgrp * 16) ^ ((d & 7) << 4)));                 \
            o[0][df] = MFMA16(pa[0][ks], vf, o[0][df]);                              \
            o[1][df] = MFMA16(pa[1][ks], vf, o[1][df]);                              \
        }                                                                            \
    __builtin_amdgcn_s_setprio(0);                                                   \
} while (0)

    // prologue: K(0)->Kb0, V(0)->Vb0, K(1)->Kb1; drain; QK(0)->sA
    STG_K(0, lds);
    STG_V(0, lds + 32768);
    STG_K(1, lds + 16384);
    __syncthreads();
    QK_TILE(sA, lds);

    for (int t = 0; t < 8; ++t) {
        const int e = 2 * t;
        // ---- even tile e (cur = sA) ----
        __syncthreads();                         // drains K(e+1), V(e) glds
        if (e < 14) STG_K(e + 2, lds);           // -> Kb0 (QK(e) done by all)
        if (e < 15) STG_V(e + 1, lds + 49152);   // -> Vb1
        if (e < 15) QK_TILE(sB, lds + 16384);    // tile e+1 from Kb1
        SM_PV(sA, lds + 32768);                  // softmax(e) + PV(e) from Vb0
        // ---- odd tile e+1 (cur = sB) ----
        __syncthreads();                         // drains K(e+2), V(e+1)
        if (e < 14) STG_K(e + 3, lds + 16384);   // -> Kb1 (K3..K15; r9 fix)
        if (e < 14) STG_V(e + 2, lds + 32768);   // -> Vb0
        if (e < 14) QK_TILE(sA, lds);            // tile e+2 from Kb0
        SM_PV(sB, lds + 49152);                  // softmax(e+1) + PV(e+1) from Vb1
    }
#undef STG_K
#undef STG_V
#undef QK_TILE
#undef SM_PV

    // ---- state to row form (row = j*16 + lgrp*4 + r) ----
    float mr[2][4], lr_[2][4];
#pragma unroll
    for (int j = 0; j < 2; ++j)
#pragma unroll
        for (int r = 0; r < 4; ++r) {
            mr[j][r]  = __shfl(m[j], lgrp * 4 + r);
            lr_[j][r] = __shfl(l[j], lgrp * 4 + r);
        }

    // ---- write bf16 unnormalized partial + f32 (m,l) ----
#pragma unroll
    for (int j = 0; j < 2; ++j)
#pragma unroll
        for (int df = 0; df < 8; ++df)
#pragma unroll
            for (int r = 0; r < 4; ++r) {
                const int qg = qb + j * 16 + lgrp * 4 + r;
                partO[((size_t)sp * 8192 + qg) * 128 + df * 16 + lrow] = f2bf(o[j][df][r]);
            }
    if (lrow == 0) {
#pragma unroll
        for (int j = 0; j < 2; ++j)
#pragma unroll
            for (int r = 0; r < 4; ++r) {
                const int qg = qb + j * 16 + lgrp * 4 + r;
                partML[((size_t)sp * 8192 + qg) * 2]     = mr[j][r];
                partML[((size_t)sp * 8192 + qg) * 2 + 1] = lr_[j][r];
            }
    }
}

// ---------------------------------------------------------------------------
// Kernel 3: merge 8 kv-split bf16 partials and normalize.
// ---------------------------------------------------------------------------
__global__ __launch_bounds__(256) void merge_kernel(
    const unsigned short* __restrict__ partO, const float* __restrict__ partML,
    float* __restrict__ out)
{
    const int gid = blockIdx.x * 256 + threadIdx.x;   // 0..262143
    const int q = gid >> 5, dc = gid & 31;
    float mv[8], lv[8];
#pragma unroll
    for (int spv = 0; spv < 8; ++spv) {
        mv[spv] = partML[((size_t)spv * 8192 + q) * 2];
        lv[spv] = partML[((size_t)spv * 8192 + q) * 2 + 1];
    }
    float M = mv[0];
#pragma unroll
    for (int spv = 1; spv < 8; ++spv) M = fmaxf(M, mv[spv]);
    float e[8], L = 0.f;
#pragma unroll
    for (int spv = 0; spv < 8; ++spv) { e[spv] = exp2_fast(mv[spv] - M); L += lv[spv] * e[spv]; }
    const float inv = 1.0f / L;
    f32x4 r = (f32x4)0.0f;
#pragma unroll
    for (int spv = 0; spv < 8; ++spv) {
        ushort4_ v = *(const ushort4_*)(partO + ((size_t)spv * 8192 + q) * 128 + dc * 4);
#pragma unroll
        for (int k = 0; k < 4; ++k) r[k] += bf2f(v[k]) * e[spv];
    }
#pragma unroll
    for (int k = 0; k < 4; ++k) r[k] *= inv;
    *(f32x4*)(out + (size_t)q * 128 + dc * 4) = r;
}

extern "C" void kernel_launch(void* const* d_in, const int* in_sizes, int n_in,
                              void* d_out, int out_size, void* d_ws, size_t ws_size,
                              hipStream_t stream)
{
    const float* X  = (const float*)d_in[0];
    const float* Wq = (const float*)d_in[1];
    const float* Wk = (const float*)d_in[2];
    const float* Wv = (const float*)d_in[3];

    char* ws = (char*)d_ws;
    const size_t QS_OFF  = 0;                                   // 2 MiB
    const size_t KB_OFF  = QS_OFF + (size_t)8192 * 128 * 2;     // 2 MiB
    const size_t VT_OFF  = KB_OFF + (size_t)8192 * 128 * 2;     // 2 MiB (V transposed)
    const size_t WB_OFF  = VT_OFF + (size_t)8192 * 128 * 2;     // 768 KiB
    const size_t PO_OFF  = WB_OFF + (size_t)3 * 128 * 1024 * 2; // 8*8192*128 bf16 = 16 MiB
    const size_t PML_OFF = PO_OFF + (size_t)8 * 8192 * 128 * 2; // 8*8192*2 f32 = 512 KiB

    unsigned short* Qs  = (unsigned short*)(ws + QS_OFF);
    unsigned short* Kb  = (unsigned short*)(ws + KB_OFF);
    unsigned short* Vt  = (unsigned short*)(ws + VT_OFF);
    unsigned short* Wb  = (unsigned short*)(ws + WB_OFF);
    unsigned short* partO = (unsigned short*)(ws + PO_OFF);
    float* partML = (float*)(ws + PML_OFF);
    float* out = (float*)d_out;

    wcvt_kernel<<<dim3(128, 3), 256, 0, stream>>>(Wq, Wk, Wv, Wb);
    qkv_kernel<<<dim3(128, 3), 256, 0, stream>>>(X, Wb, Qs, Kb, Vt);
    attn_kernel<<<dim3(512), 256, 0, stream>>>(Qs, Kb, Vt, partO, partML);
    merge_kernel<<<dim3(1024), 256, 0, stream>>>(partO, partML, out);
}